// Round 10
// baseline (184.582 us; speedup 1.0000x reference)
//
#include <hip/hip_runtime.h>
#include <hip/hip_bf16.h>

// Problem constants
#define D_MODEL 768
#define NH 12
#define HD 64
#define BATCH 4
#define SEQ 2048
#define BHN (BATCH*NH)        // 48
#define MROWS (BATCH*SEQ)     // 8192

typedef unsigned short u16;
typedef unsigned int u32;
typedef __attribute__((ext_vector_type(8))) short short8;
typedef __attribute__((ext_vector_type(4))) float f32x4;

__device__ inline u16 f2bf(float f){
  union { __hip_bfloat16 h; u16 u; } cv; cv.h = __float2bfloat16(f); return cv.u;
}
__device__ inline u32 pack_bf2(float a, float b){
  return (u32)f2bf(a) | ((u32)f2bf(b) << 16);
}

// async global->LDS, 16B per lane. LDS dest = wave-uniform base + lane*16.
__device__ inline void async_copy16(const void* g, void* l){
  __builtin_amdgcn_global_load_lds(
      (const __attribute__((address_space(1))) void*)g,
      (__attribute__((address_space(3))) void*)l, 16, 0, 0);
}

// ---------------- cast fp32 -> bf16, vectorized x4 ----------------
__global__ void cast4_kernel(const float* __restrict__ in, u16* __restrict__ out, int n4){
  int i = blockIdx.x*blockDim.x + threadIdx.x;
  if (i < n4){
    const float4 v = ((const float4*)in)[i];
    ushort4 o;
    o.x = f2bf(v.x); o.y = f2bf(v.y); o.z = f2bf(v.z); o.w = f2bf(v.w);
    ((ushort4*)out)[i] = o;
  }
}

// ---------------- transpose + cast: W[K][N] fp32 -> Wt[N][K] bf16 ----------------
__global__ void transpose_cast_kernel(const float* __restrict__ w, u16* __restrict__ wt,
                                      int K, int N){
  __shared__ u16 tile[64][65];
  int k0 = blockIdx.x*64, n0 = blockIdx.y*64;
  int c = threadIdx.x & 63, r0 = threadIdx.x >> 6;
  #pragma unroll
  for (int r = r0; r < 64; r += 4)
    tile[c][r] = f2bf(w[(size_t)(k0+r)*N + n0 + c]);
  __syncthreads();
  #pragma unroll
  for (int r = r0; r < 64; r += 4)
    wt[(size_t)(n0+r)*K + k0 + c] = tile[r][c];
}

// ---------------- 256x256 8-phase GEMM (QKV): C = A @ Bt^T, scatter epilogue ----
// 512 threads = 8 waves (2M x 4N), per-wave output 128x64 (8x4 frags).
// BK=64 K-tiles, 12 tiles (K=768). LDS 128KB dynamic: 2 bufs x {A 32KB, B 32KB},
// rows 128B XOR-swizzled via pre-swizzled gload source (col8 ^= row&7).
// 4 phases per tile; per phase: [ds_read subtile][stage 1 half][bar][lgkm0]
// [setprio 16 MFMA][bar]. vmcnt(2) once per tile at P4 (derived: stages get
// 2-6 phases of slack; counted per-wave, barrier broadcasts arrival).
__launch_bounds__(512, 2)
__global__ void gemm256_qkv(const u16* __restrict__ A, const u16* __restrict__ Bt,
                            const float* __restrict__ bias,
                            u16* __restrict__ oq, u16* __restrict__ ok, u16* __restrict__ ovt,
                            int M, int N, int K)
{
  extern __shared__ char smem[];   // 131072: buf c at c*65536 {A0,A1,B0,B1 16KB each}
  const int tid = threadIdx.x, wid = tid>>6, lane = tid&63;
  const int wm = wid>>2, wn = wid&3;
  const int lr = lane&15, lg = lane>>4;
  // XCD swizzle (288 % 8 == 0 -> simple form bijective)
  const int swz = ((int)blockIdx.x & 7)*36 + ((int)blockIdx.x >> 3);
  const int m0 = (swz & 31) * 256;
  const int n0 = (swz >> 5) * 256;
  const int c8s = (lane&7) ^ (lane>>3);      // staging source granule swizzle
  const int srowb = wid*16 + (lane>>3);      // staging row within 128-row half

  f32x4 acc[8][4] = {};

  auto stageA = [&](int kt, int buf, int half){
    char* dst = smem + buf*65536 + half*16384 + (wid*16)*128;
    const u16* src = A + (size_t)(m0 + half*128 + srowb)*K + kt + c8s*8;
    async_copy16(src,                dst);
    async_copy16(src + (size_t)8*K,  dst + 1024);
  };
  auto stageB = [&](int kt, int buf, int half){
    char* dst = smem + buf*65536 + 32768 + half*16384 + (wid*16)*128;
    const u16* src = Bt + (size_t)(n0 + half*128 + srowb)*K + kt + c8s*8;
    async_copy16(src,                dst);
    async_copy16(src + (size_t)8*K,  dst + 1024);
  };

  const int NT = K >> 6;   // 12
  // prologue: full tile 0 + B halves of tile 1, then wait for tile 0
  stageA(0, 0, 0); stageA(0, 0, 1); stageB(0, 0, 0); stageB(0, 0, 1);
  stageB(64, 1, 0); stageB(64, 1, 1);
  asm volatile("s_waitcnt vmcnt(4)" ::: "memory");
  __builtin_amdgcn_sched_barrier(0);
  __builtin_amdgcn_s_barrier();

  short8 a2[4][2], b2[4][2];

  #pragma unroll 1
  for (int t = 0; t < NT; t++){
    const int c = t & 1, o = c ^ 1;
    const char* Ab = smem + c*65536;          // 256 rows x 128B
    const char* Bb = Ab + 32768;
    const int kt1 = (t+1) << 6, kt2 = (t+2) << 6;

    // ---------------- P1: read a[0:4]+b[0:2]; stage A0(t+1) ----------------
    #pragma unroll
    for (int mi = 0; mi < 4; mi++){
      int r = wm*128 + mi*16 + lr;
      a2[mi][0] = *(const short8*)(Ab + r*128 + (( 0 + lg*16) ^ ((r&7)<<4)));
      a2[mi][1] = *(const short8*)(Ab + r*128 + ((64 + lg*16) ^ ((r&7)<<4)));
    }
    #pragma unroll
    for (int ni = 0; ni < 2; ni++){
      int r = wn*64 + ni*16 + lr;
      b2[ni][0] = *(const short8*)(Bb + r*128 + (( 0 + lg*16) ^ ((r&7)<<4)));
      b2[ni][1] = *(const short8*)(Bb + r*128 + ((64 + lg*16) ^ ((r&7)<<4)));
    }
    if (t+1 < NT) stageA(kt1, o, 0);
    __builtin_amdgcn_s_barrier();
    asm volatile("s_waitcnt lgkmcnt(0)" ::: "memory");
    __builtin_amdgcn_sched_barrier(0);
    __builtin_amdgcn_s_setprio(1);
    #pragma unroll
    for (int mi = 0; mi < 4; mi++)
      #pragma unroll
      for (int ni = 0; ni < 2; ni++){
        acc[mi][ni] = __builtin_amdgcn_mfma_f32_16x16x32_bf16(a2[mi][0], b2[ni][0], acc[mi][ni], 0,0,0);
        acc[mi][ni] = __builtin_amdgcn_mfma_f32_16x16x32_bf16(a2[mi][1], b2[ni][1], acc[mi][ni], 0,0,0);
      }
    __builtin_amdgcn_s_setprio(0);
    __builtin_amdgcn_s_barrier();

    // ---------------- P2: read b[2:4]; stage A1(t+1) ----------------
    #pragma unroll
    for (int ni = 2; ni < 4; ni++){
      int r = wn*64 + ni*16 + lr;
      b2[ni][0] = *(const short8*)(Bb + r*128 + (( 0 + lg*16) ^ ((r&7)<<4)));
      b2[ni][1] = *(const short8*)(Bb + r*128 + ((64 + lg*16) ^ ((r&7)<<4)));
    }
    if (t+1 < NT) stageA(kt1, o, 1);
    __builtin_amdgcn_s_barrier();
    asm volatile("s_waitcnt lgkmcnt(0)" ::: "memory");
    __builtin_amdgcn_sched_barrier(0);
    __builtin_amdgcn_s_setprio(1);
    #pragma unroll
    for (int mi = 0; mi < 4; mi++)
      #pragma unroll
      for (int ni = 2; ni < 4; ni++){
        acc[mi][ni] = __builtin_amdgcn_mfma_f32_16x16x32_bf16(a2[mi][0], b2[ni][0], acc[mi][ni], 0,0,0);
        acc[mi][ni] = __builtin_amdgcn_mfma_f32_16x16x32_bf16(a2[mi][1], b2[ni][1], acc[mi][ni], 0,0,0);
      }
    __builtin_amdgcn_s_setprio(0);
    __builtin_amdgcn_s_barrier();

    // ---------------- P3: read a[4:8] (reuse a2); stage B0(t+2) ----------------
    #pragma unroll
    for (int mi = 0; mi < 4; mi++){
      int r = wm*128 + (mi+4)*16 + lr;
      a2[mi][0] = *(const short8*)(Ab + r*128 + (( 0 + lg*16) ^ ((r&7)<<4)));
      a2[mi][1] = *(const short8*)(Ab + r*128 + ((64 + lg*16) ^ ((r&7)<<4)));
    }
    if (t+2 < NT) stageB(kt2, c, 0);
    __builtin_amdgcn_s_barrier();
    asm volatile("s_waitcnt lgkmcnt(0)" ::: "memory");
    __builtin_amdgcn_sched_barrier(0);
    __builtin_amdgcn_s_setprio(1);
    #pragma unroll
    for (int mi = 0; mi < 4; mi++)
      #pragma unroll
      for (int ni = 0; ni < 2; ni++){
        acc[4+mi][ni] = __builtin_amdgcn_mfma_f32_16x16x32_bf16(a2[mi][0], b2[ni][0], acc[4+mi][ni], 0,0,0);
        acc[4+mi][ni] = __builtin_amdgcn_mfma_f32_16x16x32_bf16(a2[mi][1], b2[ni][1], acc[4+mi][ni], 0,0,0);
      }
    __builtin_amdgcn_s_setprio(0);
    __builtin_amdgcn_s_barrier();

    // ---------------- P4: vmcnt; stage B1(t+2); MFMA Q3 ----------------
    if (t+2 < NT){
      asm volatile("s_waitcnt vmcnt(2)" ::: "memory");
    } else {
      asm volatile("s_waitcnt vmcnt(0)" ::: "memory");
    }
    __builtin_amdgcn_sched_barrier(0);
    if (t+2 < NT) stageB(kt2, c, 1);
    __builtin_amdgcn_s_barrier();
    __builtin_amdgcn_s_setprio(1);
    #pragma unroll
    for (int mi = 0; mi < 4; mi++)
      #pragma unroll
      for (int ni = 2; ni < 4; ni++){
        acc[4+mi][ni] = __builtin_amdgcn_mfma_f32_16x16x32_bf16(a2[mi][0], b2[ni][0], acc[4+mi][ni], 0,0,0);
        acc[4+mi][ni] = __builtin_amdgcn_mfma_f32_16x16x32_bf16(a2[mi][1], b2[ni][1], acc[4+mi][ni], 0,0,0);
      }
    __builtin_amdgcn_s_setprio(0);
    __builtin_amdgcn_s_barrier();
  }

  // epilogue: QKV scatter (C row=(lane>>4)*4+j, col=lane&15 per frag)
  #pragma unroll
  for (int mi = 0; mi < 8; mi++)
  #pragma unroll
  for (int ni = 0; ni < 4; ni++)
  #pragma unroll
  for (int j = 0; j < 4; j++){
    int m = m0 + wm*128 + mi*16 + lg*4 + j;
    int n = n0 + wn*64 + ni*16 + lr;
    float v = acc[mi][ni][j] + bias[n];
    int b_ = m >> 11, s = m & 2047;
    int ty = (n >= 1536) ? 2 : (n >= 768 ? 1 : 0);
    int hn = n - ty*768;
    int h = hn >> 6, d = hn & 63;
    size_t base = (size_t)(b_*NH + h);
    if (ty == 0)      oq [(base*SEQ + s)*HD + d] = f2bf(v * 0.1803368801f); // fold 0.125*log2e into Q
    else if (ty == 1) ok [(base*SEQ + s)*HD + d] = f2bf(v);
    else              ovt[(base*HD + d)*SEQ + s] = f2bf(v);   // V stored transposed
  }
}

// ---------------- bf16 GEMM (out-proj): C[M,N] = A[M,K] @ Bt[N,K]^T ----------------
// 128x128 tile, BK=32, 3-buffer counted-vmcnt pipeline (unchanged from R9).
template<int EPI>
__launch_bounds__(256)
__global__ void gemm_bf16(const u16* __restrict__ A, const u16* __restrict__ Bt,
                          const float* __restrict__ bias, float* __restrict__ outf,
                          int M, int N, int K)
{
  __shared__ alignas(16) char smem[49152];   // 3 bufs x (A 8KB + B 8KB)
  const int tid = threadIdx.x, wave = tid>>6, lane = tid&63;
  const int lr = lane&15, lg = lane>>4;
  const int m0 = blockIdx.x*128, n0 = blockIdx.y*128;
  const int wr = (wave>>1)*64, wc = (wave&1)*64;
  f32x4 acc[4][4] = {};
  const int srow = wave*32 + (lane>>2);
  const int schk = (lane&3) ^ ((lane>>3)&3);
  const int fo   = ((lg ^ ((lr>>1)&3)) << 4);

  auto stage = [&](int kt, int buf){
    char* Ab = smem + buf*16384;
    char* Bb = Ab + 8192;
    #pragma unroll
    for (int i = 0; i < 2; i++){
      int r = srow + i*16;
      async_copy16(A  + (size_t)(m0 + r)*K + kt + schk*8, Ab + (wave*32 + i*16)*64);
      async_copy16(Bt + (size_t)(n0 + r)*K + kt + schk*8, Bb + (wave*32 + i*16)*64);
    }
  };

  const int NT = K >> 5;
  stage(0, 0);
  if (NT > 1) stage(32, 1);
  int c = 0, sb = 2;
  for (int t = 0; t < NT; t++){
    if (t+1 < NT) asm volatile("s_waitcnt vmcnt(4)" ::: "memory");
    else          asm volatile("s_waitcnt vmcnt(0)" ::: "memory");
    __builtin_amdgcn_s_barrier();
    if (t+2 < NT){
      stage((t+2)<<5, sb);
      sb = (sb==2) ? 0 : sb+1;
    }

    const char* Ac = smem + c*16384;
    const char* Bc = Ac + 8192;
    c = (c==2) ? 0 : c+1;
    short8 a[4], b[4];
    #pragma unroll
    for (int mi = 0; mi < 4; mi++)
      a[mi] = *(const short8*)(Ac + (wr + mi*16 + lr)*64 + fo);
    #pragma unroll
    for (int ni = 0; ni < 4; ni++)
      b[ni] = *(const short8*)(Bc + (wc + ni*16 + lr)*64 + fo);
    #pragma unroll
    for (int mi = 0; mi < 4; mi++)
      #pragma unroll
      for (int ni = 0; ni < 4; ni++)
        acc[mi][ni] = __builtin_amdgcn_mfma_f32_16x16x32_bf16(a[mi], b[ni], acc[mi][ni], 0, 0, 0);
  }

  #pragma unroll
  for (int mi = 0; mi < 4; mi++)
  #pragma unroll
  for (int ni = 0; ni < 4; ni++)
  #pragma unroll
  for (int j = 0; j < 4; j++){
    int m = m0 + wr + mi*16 + lg*4 + j;
    int n = n0 + wc + ni*16 + lr;
    outf[(size_t)m*N + n] = acc[mi][ni][j] + bias[n];
  }
}

// ---------------- flash attention: merged causal pair-sweep (unchanged) ----------------
__launch_bounds__(256, 3)
__global__ void attn_kernel(const u16* __restrict__ q, const u16* __restrict__ k,
                            const u16* __restrict__ vt, u16* __restrict__ aout)
{
  __shared__ alignas(16) char smem[53248];
  const int b1 = blockIdx.x;                 // 0..767
  const int xcd = b1 & 7, grp = b1 >> 3;     // grp 0..95
  const int bh = xcd*6 + (grp >> 4);         // 6 heads per XCD (L2 locality)
  const int p  = grp & 15;                   // lo tile index 0..15
  const int hi = 31 - p;                     // hi tile index 16..31
  const int tid = threadIdx.x, wave = tid>>6, lane = tid&63;
  const int lr = lane&15, lg = lane>>4;
  const int b_ = bh / NH, h_ = bh % NH;
  const u16* qp = q  + (size_t)bh*SEQ*HD;
  const u16* kp = k  + (size_t)bh*SEQ*HD;
  const u16* vp = vt + (size_t)bh*HD*SEQ;
  char* Pw = smem + 32768 + wave*5120;
  const int fswz = (lr&7)<<4;
  const int c8s = (lane&7) ^ (lane>>3);
  const int nkv = hi + 1;

  auto stageKV = [&](int kv0, int buf){
    char* Kb = smem + buf*16384;
    char* Vb = Kb + 8192;
    #pragma unroll
    for (int r = 0; r < 2; r++){
      int row = wave*16 + r*8 + (lane>>3);
      async_copy16(kp + (size_t)(kv0 + row)*HD + c8s*8, Kb + (wave*16 + r*8)*128);
      async_copy16(vp + (size_t)row*SEQ + kv0 + c8s*8,  Vb + (wave*16 + r*8)*128);
    }
  };

  const int qrow[2] = { hi*64 + wave*16 + lr, p*64 + wave*16 + lr };

  short8 bq[2][2];
  #pragma unroll
  for (int h = 0; h < 2; h++)
    #pragma unroll
    for (int ks = 0; ks < 2; ks++)
      bq[h][ks] = *(const short8*)(qp + (size_t)qrow[h]*HD + ks*32 + lg*8);

  float mrow[2] = {-INFINITY, -INFINITY};
  float lsum[2] = {0.f, 0.f};
  f32x4 o[4][2] = {};

  stageKV(0, 0);

  auto softmax_pack = [&](f32x4 (&s)[4][2], int h, bool domask, int kv0, int qr){
    if (domask){
      #pragma unroll
      for (int ni = 0; ni < 4; ni++)
        #pragma unroll
        for (int jj = 0; jj < 4; jj++){
          int col = kv0 + ni*16 + lg*4 + jj;
          if (col > qr) s[ni][h][jj] = -1e30f;
        }
    }
    float v0 = fmaxf(fmaxf(s[0][h][0], s[0][h][1]), fmaxf(s[0][h][2], s[0][h][3]));
    float v1 = fmaxf(fmaxf(s[1][h][0], s[1][h][1]), fmaxf(s[1][h][2], s[1][h][3]));
    float v2 = fmaxf(fmaxf(s[2][h][0], s[2][h][1]), fmaxf(s[2][h][2], s[2][h][3]));
    float v3 = fmaxf(fmaxf(s[3][h][0], s[3][h][1]), fmaxf(s[3][h][2], s[3][h][3]));
    float vloc = fmaxf(fmaxf(v0, v1), fmaxf(v2, v3));
    if (!__all(vloc - mrow[h] <= 8.0f)){
      float v = fmaxf(vloc, __shfl_xor(vloc, 16));
      v = fmaxf(v, __shfl_xor(v, 32));
      float mn = fmaxf(mrow[h], v);
      float alpha = __builtin_amdgcn_exp2f(mrow[h] - mn);
      mrow[h] = mn;
      lsum[h] *= alpha;
      #pragma unroll
      for (int ni = 0; ni < 4; ni++)
        #pragma unroll
        for (int jj = 0; jj < 4; jj++)
          o[ni][h][jj] *= alpha;
    }
    const float mn = mrow[h];
    char* hb = Pw + h*2560;
    float psum = 0.f;
    #pragma unroll
    for (int ni = 0; ni < 4; ni++){
      float p0 = __builtin_amdgcn_exp2f(s[ni][h][0] - mn);
      float p1 = __builtin_amdgcn_exp2f(s[ni][h][1] - mn);
      float p2 = __builtin_amdgcn_exp2f(s[ni][h][2] - mn);
      float p3 = __builtin_amdgcn_exp2f(s[ni][h][3] - mn);
      psum += (p0+p1) + (p2+p3);
      int tl = lr + 16*(((ni&1)<<1) | (lg>>1));
      int wb = ((ni>>1)<<2) | ((lg&1)<<1);
      *(u32*)(hb + tl*40 + wb*4)     = pack_bf2(p0, p1);
      *(u32*)(hb + tl*40 + wb*4 + 4) = pack_bf2(p2, p3);
    }
    lsum[h] += psum;
  };

  auto read_pb = [&](int h, short8& r0, short8& r1){
    const char* hb = Pw + h*2560 + (size_t)lane*40;
    union { u32 w[4]; short8 v; } a, b;
    a.w[0] = *(const u32*)(hb);      a.w[1] = *(const u32*)(hb + 4);
    a.w[2] = *(const u32*)(hb + 8);  a.w[3] = *(const u32*)(hb + 12);
    b.w[0] = *(const u32*)(hb + 16); b.w[1] = *(const u32*)(hb + 20);
    b.w[2] = *(const u32*)(hb + 24); b.w[3] = *(const u32*)(hb + 28);
    r0 = a.v; r1 = b.v;
  };

  int kvb = 0;

  #pragma unroll 1
  for (; kvb <= p; kvb++){
    const int c = kvb & 1;
    const int kv0 = kvb*64;
    asm volatile("s_waitcnt vmcnt(0)" ::: "memory");
    __builtin_amdgcn_s_barrier();
    if (kvb+1 < nkv) stageKV(kv0 + 64, c^1);

    const char* Kb = smem + c*16384;
    const char* Vb = Kb + 8192;

    f32x4 s[4][2] = {};
    __builtin_amdgcn_s_setprio(1);
    #pragma unroll
    for (int ni = 0; ni < 4; ni++){
      short8 k0 = *(const short8*)(Kb + (ni*16+lr)*128 + ((lg*16) ^ fswz));
      short8 k1 = *(const short8*)(Kb + (ni*16+lr)*128 + ((64 + lg*16) ^ fswz));
      #pragma unroll
      for (int h = 0; h < 2; h++){
        s[ni][h] = __builtin_amdgcn_mfma_f32_16x16x32_bf16(k0, bq[h][0], s[ni][h], 0,0,0);
        s[ni][h] = __builtin_amdgcn_mfma_f32_16x16x32_bf16(k1, bq[h][1], s[ni][h], 0,0,0);
      }
    }
    __builtin_amdgcn_s_setprio(0);

    softmax_pack(s, 0, false, kv0, qrow[0]);
    softmax_pack(s, 1, kvb == p, kv0, qrow[1]);

    short8 pb[2][2];
    read_pb(0, pb[0][0], pb[0][1]);
    read_pb(1, pb[1][0], pb[1][1]);

    __builtin_amdgcn_s_setprio(1);
    #pragma unroll
    for (int ni = 0; ni < 4; ni++){
      short8 v0 = *(const short8*)(Vb + (ni*16+lr)*128 + ((lg*16) ^ fswz));
      short8 v1 = *(const short8*)(Vb + (ni*16+lr)*128 + ((64 + lg*16) ^ fswz));
      #pragma unroll
      for (int h = 0; h < 2; h++){
        o[ni][h] = __builtin_amdgcn_mfma_f32_16x16x32_bf16(v0, pb[h][0], o[ni][h], 0,0,0);
        o[ni][h] = __builtin_amdgcn_mfma_f32_16x16x32_bf16(v1, pb[h][1], o[ni][h], 0,0,0);
      }
    }
    __builtin_amdgcn_s_setprio(0);
  }

  #pragma unroll 1
  for (; kvb < nkv; kvb++){
    const int c = kvb & 1;
    const int kv0 = kvb*64;
    asm volatile("s_waitcnt vmcnt(0)" ::: "memory");
    __builtin_amdgcn_s_barrier();
    if (kvb+1 < nkv) stageKV(kv0 + 64, c^1);

    const char* Kb = smem + c*16384;
    const char* Vb = Kb + 8192;

    f32x4 s[4][2];
    #pragma unroll
    for (int ni = 0; ni < 4; ni++) s[ni][0] = (f32x4){0.f,0.f,0.f,0.f};
    __builtin_amdgcn_s_setprio(1);
    #pragma unroll
    for (int ni = 0; ni < 4; ni++){
      short8 k0 = *(const short8*)(Kb + (ni*16+lr)*128 + ((lg*16) ^ fswz));
      short8 k1 = *(const short8*)(Kb + (ni*16+lr)*128 + ((64 + lg*16) ^ fswz));
      s[ni][0] = __builtin_amdgcn_mfma_f32_16x16x32_bf16(k0, bq[0][0], s[ni][0], 0,0,0);
      s[ni][0] = __builtin_amdgcn_mfma_f32_16x16x32_bf16(k1, bq[0][1], s[ni][0], 0,0,0);
    }
    __builtin_amdgcn_s_setprio(0);

    softmax_pack(s, 0, kvb == hi, kv0, qrow[0]);

    short8 pb0, pb1;
    read_pb(0, pb0, pb1);

    __builtin_amdgcn_s_setprio(1);
    #pragma unroll
    for (int ni = 0; ni < 4; ni++){
      short8 v0 = *(const short8*)(Vb + (ni*16+lr)*128 + ((lg*16) ^ fswz));
      short8 v1 = *(const short8*)(Vb + (ni*16+lr)*128 + ((64 + lg*16) ^ fswz));
      o[ni][0] = __builtin_amdgcn_mfma_f32_16x16x32_bf16(v0, pb0, o[ni][0], 0,0,0);
      o[ni][0] = __builtin_amdgcn_mfma_f32_16x16x32_bf16(v1, pb1, o[ni][0], 0,0,0);
    }
    __builtin_amdgcn_s_setprio(0);
  }

  #pragma unroll
  for (int h = 0; h < 2; h++){
    float ls = lsum[h];
    ls += __shfl_xor(ls, 16);
    ls += __shfl_xor(ls, 32);
    float inv = 1.0f / ls;
    u16* orow = aout + ((size_t)b_*SEQ + qrow[h])*D_MODEL + h_*HD;
    #pragma unroll
    for (int ni = 0; ni < 4; ni++){
      ushort4 w;
      w.x = f2bf(o[ni][h][0]*inv);
      w.y = f2bf(o[ni][h][1]*inv);
      w.z = f2bf(o[ni][h][2]*inv);
      w.w = f2bf(o[ni][h][3]*inv);
      *(ushort4*)(orow + ni*16 + lg*4) = w;
    }
  }
}

extern "C" void kernel_launch(void* const* d_in, const int* in_sizes, int n_in,
                              void* d_out, int out_size, void* d_ws, size_t ws_size,
                              hipStream_t stream)
{
  const float* x    = (const float*)d_in[0];
  const float* Wqkv = (const float*)d_in[1];
  const float* bqkv = (const float*)d_in[2];
  const float* Wout = (const float*)d_in[3];
  const float* bout = (const float*)d_in[4];
  float* out = (float*)d_out;
  char* ws = (char*)d_ws;

  // workspace layout (bytes)
  u16* x_bf   = (u16*)(ws + 0);          // 8192x768   bf16 = 12,582,912
  u16* wqkv_t = (u16*)(ws + 12582912);   // 2304x768   bf16 =  3,538,944
  u16* wout_t = (u16*)(ws + 16121856);   //  768x768   bf16 =  1,179,648
  u16* qb     = (u16*)(ws + 17301504);   // [48][2048][64]  = 12,582,912
  u16* kb     = (u16*)(ws + 29884416);   // [48][2048][64]  = 12,582,912
  u16* vtb    = (u16*)(ws + 42467328);   // [48][64][2048]  = 12,582,912
  u16* attnb  = (u16*)(ws + 55050240);   // 8192x768   bf16 = 12,582,912

  // allow 128KB dynamic LDS for the 8-phase GEMM (idempotent)
  hipFuncSetAttribute((const void*)gemm256_qkv,
                      hipFuncAttributeMaxDynamicSharedMemorySize, 131072);

  cast4_kernel<<<6144, 256, 0, stream>>>(x, x_bf, (BATCH*SEQ*D_MODEL)/4);
  transpose_cast_kernel<<<dim3(12, 36), 256, 0, stream>>>(Wqkv, wqkv_t, 768, 2304);
  transpose_cast_kernel<<<dim3(12, 12), 256, 0, stream>>>(Wout, wout_t, 768, 768);

  gemm256_qkv<<<288, 512, 131072, stream>>>(x_bf, wqkv_t, bqkv,
                                            qb, kb, vtb, MROWS, 3*D_MODEL, D_MODEL);

  attn_kernel<<<768, 256, 0, stream>>>(qb, kb, vtb, attnb);

  gemm_bf16<0><<<dim3(64, 6), 256, 0, stream>>>(attnb, wout_t, bout, out,
                                                MROWS, D_MODEL, D_MODEL);
}

// Round 11
// 138.026 us; speedup vs baseline: 1.3373x; 1.3373x over previous
//
#include <hip/hip_runtime.h>
#include <hip/hip_bf16.h>

// Problem constants
#define D_MODEL 768
#define NH 12
#define HD 64
#define BATCH 4
#define SEQ 2048
#define BHN (BATCH*NH)        // 48
#define MROWS (BATCH*SEQ)     // 8192

typedef unsigned short u16;
typedef unsigned int u32;
typedef __attribute__((ext_vector_type(8))) short short8;
typedef __attribute__((ext_vector_type(4))) float f32x4;

__device__ inline u16 f2bf(float f){
  union { __hip_bfloat16 h; u16 u; } cv; cv.h = __float2bfloat16(f); return cv.u;
}
__device__ inline u32 pack_bf2(float a, float b){
  return (u32)f2bf(a) | ((u32)f2bf(b) << 16);
}

// async global->LDS, 16B per lane. LDS dest = wave-uniform base + lane*16.
__device__ inline void async_copy16(const void* g, void* l){
  __builtin_amdgcn_global_load_lds(
      (const __attribute__((address_space(1))) void*)g,
      (__attribute__((address_space(3))) void*)l, 16, 0, 0);
}

// ---------------- cast fp32 -> bf16, vectorized x4 ----------------
__global__ void cast4_kernel(const float* __restrict__ in, u16* __restrict__ out, int n4){
  int i = blockIdx.x*blockDim.x + threadIdx.x;
  if (i < n4){
    const float4 v = ((const float4*)in)[i];
    ushort4 o;
    o.x = f2bf(v.x); o.y = f2bf(v.y); o.z = f2bf(v.z); o.w = f2bf(v.w);
    ((ushort4*)out)[i] = o;
  }
}

// ---------------- transpose + cast: W[K][N] fp32 -> Wt[N][K] bf16 ----------------
__global__ void transpose_cast_kernel(const float* __restrict__ w, u16* __restrict__ wt,
                                      int K, int N){
  __shared__ u16 tile[64][65];
  int k0 = blockIdx.x*64, n0 = blockIdx.y*64;
  int c = threadIdx.x & 63, r0 = threadIdx.x >> 6;
  #pragma unroll
  for (int r = r0; r < 64; r += 4)
    tile[c][r] = f2bf(w[(size_t)(k0+r)*N + n0 + c]);
  __syncthreads();
  #pragma unroll
  for (int r = r0; r < 64; r += 4)
    wt[(size_t)(n0+r)*K + k0 + c] = tile[r][c];
}

// ---------------- bf16 GEMM: C[M,N] = A[M,K] @ Bt[N,K]^T ----------------
// 128x128 tile, BK=32, TWO-buffer LDS (32KB total -> 5 blocks/CU capacity:
// gemm<1>'s 1152 blocks are ALL resident in one round, zero tail), plus the
// granule XOR-swizzle (conflicts=0, verified R9). vmcnt(0)+barrier per step:
// with 5 blocks/CU the TLP hides the drain (R8 measured equal to counted-vmcnt).
template<int EPI>
__launch_bounds__(256)
__global__ void gemm_bf16(const u16* __restrict__ A, const u16* __restrict__ Bt,
                          const float* __restrict__ bias, float* __restrict__ outf,
                          u16* __restrict__ oq, u16* __restrict__ ok, u16* __restrict__ ovt,
                          int M, int N, int K)
{
  __shared__ alignas(16) char smem[32768];   // 2 bufs x (A 8KB + B 8KB)
  const int tid = threadIdx.x, wave = tid>>6, lane = tid&63;
  const int lr = lane&15, lg = lane>>4;
  const int m0 = blockIdx.x*128, n0 = blockIdx.y*128;
  const int wr = (wave>>1)*64, wc = (wave&1)*64;
  f32x4 acc[4][4] = {};
  const int srow = wave*32 + (lane>>2);              // staging row (+i*16)
  const int schk = (lane&3) ^ ((lane>>3)&3);         // swizzled source granule
  const int fo   = ((lg ^ ((lr>>1)&3)) << 4);        // swizzled frag byte offset

  auto stage = [&](int kt, int buf){
    char* Ab = smem + buf*16384;
    char* Bb = Ab + 8192;
    #pragma unroll
    for (int i = 0; i < 2; i++){
      int r = srow + i*16;
      async_copy16(A  + (size_t)(m0 + r)*K + kt + schk*8, Ab + (wave*32 + i*16)*64);
      async_copy16(Bt + (size_t)(n0 + r)*K + kt + schk*8, Bb + (wave*32 + i*16)*64);
    }
  };

  const int NT = K >> 5;
  stage(0, 0);
  for (int t = 0; t < NT; t++){
    const int c = t & 1;
    asm volatile("s_waitcnt vmcnt(0)" ::: "memory");
    __builtin_amdgcn_s_barrier();
    if (t+1 < NT) stage((t+1)<<5, c^1);

    const char* Ac = smem + c*16384;
    const char* Bc = Ac + 8192;
    short8 a[4], b[4];
    #pragma unroll
    for (int mi = 0; mi < 4; mi++)
      a[mi] = *(const short8*)(Ac + (wr + mi*16 + lr)*64 + fo);
    #pragma unroll
    for (int ni = 0; ni < 4; ni++)
      b[ni] = *(const short8*)(Bc + (wc + ni*16 + lr)*64 + fo);
    #pragma unroll
    for (int mi = 0; mi < 4; mi++)
      #pragma unroll
      for (int ni = 0; ni < 4; ni++)
        acc[mi][ni] = __builtin_amdgcn_mfma_f32_16x16x32_bf16(a[mi], b[ni], acc[mi][ni], 0, 0, 0);
  }

  // epilogue: C row = (lane>>4)*4 + j, col = lane&15  [verified C/D layout]
  #pragma unroll
  for (int mi = 0; mi < 4; mi++)
  #pragma unroll
  for (int ni = 0; ni < 4; ni++)
  #pragma unroll
  for (int j = 0; j < 4; j++){
    int m = m0 + wr + mi*16 + lg*4 + j;
    int n = n0 + wc + ni*16 + lr;
    float v = acc[mi][ni][j] + bias[n];
    if (EPI == 0){
      outf[(size_t)m*N + n] = v;
    } else {
      int b_ = m >> 11, s = m & 2047;
      int ty = (n >= 1536) ? 2 : (n >= 768 ? 1 : 0);
      int hn = n - ty*768;
      int h = hn >> 6, d = hn & 63;
      size_t base = (size_t)(b_*NH + h);
      if (ty == 0)      oq [(base*SEQ + s)*HD + d] = f2bf(v * 0.1803368801f); // fold 0.125*log2e into Q
      else if (ty == 1) ok [(base*SEQ + s)*HD + d] = f2bf(v);
      else              ovt[(base*HD + d)*SEQ + s] = f2bf(v);   // V stored transposed
    }
  }
}

// ---------------- flash attention: merged causal pair-sweep (unchanged) ----------------
__launch_bounds__(256, 3)
__global__ void attn_kernel(const u16* __restrict__ q, const u16* __restrict__ k,
                            const u16* __restrict__ vt, u16* __restrict__ aout)
{
  __shared__ alignas(16) char smem[53248];
  const int b1 = blockIdx.x;                 // 0..767
  const int xcd = b1 & 7, grp = b1 >> 3;     // grp 0..95
  const int bh = xcd*6 + (grp >> 4);         // 6 heads per XCD (L2 locality)
  const int p  = grp & 15;                   // lo tile index 0..15
  const int hi = 31 - p;                     // hi tile index 16..31
  const int tid = threadIdx.x, wave = tid>>6, lane = tid&63;
  const int lr = lane&15, lg = lane>>4;
  const int b_ = bh / NH, h_ = bh % NH;
  const u16* qp = q  + (size_t)bh*SEQ*HD;
  const u16* kp = k  + (size_t)bh*SEQ*HD;
  const u16* vp = vt + (size_t)bh*HD*SEQ;
  char* Pw = smem + 32768 + wave*5120;
  const int fswz = (lr&7)<<4;
  const int c8s = (lane&7) ^ (lane>>3);
  const int nkv = hi + 1;

  auto stageKV = [&](int kv0, int buf){
    char* Kb = smem + buf*16384;
    char* Vb = Kb + 8192;
    #pragma unroll
    for (int r = 0; r < 2; r++){
      int row = wave*16 + r*8 + (lane>>3);
      async_copy16(kp + (size_t)(kv0 + row)*HD + c8s*8, Kb + (wave*16 + r*8)*128);
      async_copy16(vp + (size_t)row*SEQ + kv0 + c8s*8,  Vb + (wave*16 + r*8)*128);
    }
  };

  const int qrow[2] = { hi*64 + wave*16 + lr, p*64 + wave*16 + lr };

  short8 bq[2][2];
  #pragma unroll
  for (int h = 0; h < 2; h++)
    #pragma unroll
    for (int ks = 0; ks < 2; ks++)
      bq[h][ks] = *(const short8*)(qp + (size_t)qrow[h]*HD + ks*32 + lg*8);

  float mrow[2] = {-INFINITY, -INFINITY};
  float lsum[2] = {0.f, 0.f};
  f32x4 o[4][2] = {};

  stageKV(0, 0);

  auto softmax_pack = [&](f32x4 (&s)[4][2], int h, bool domask, int kv0, int qr){
    if (domask){
      #pragma unroll
      for (int ni = 0; ni < 4; ni++)
        #pragma unroll
        for (int jj = 0; jj < 4; jj++){
          int col = kv0 + ni*16 + lg*4 + jj;
          if (col > qr) s[ni][h][jj] = -1e30f;
        }
    }
    float v0 = fmaxf(fmaxf(s[0][h][0], s[0][h][1]), fmaxf(s[0][h][2], s[0][h][3]));
    float v1 = fmaxf(fmaxf(s[1][h][0], s[1][h][1]), fmaxf(s[1][h][2], s[1][h][3]));
    float v2 = fmaxf(fmaxf(s[2][h][0], s[2][h][1]), fmaxf(s[2][h][2], s[2][h][3]));
    float v3 = fmaxf(fmaxf(s[3][h][0], s[3][h][1]), fmaxf(s[3][h][2], s[3][h][3]));
    float vloc = fmaxf(fmaxf(v0, v1), fmaxf(v2, v3));
    if (!__all(vloc - mrow[h] <= 8.0f)){
      float v = fmaxf(vloc, __shfl_xor(vloc, 16));
      v = fmaxf(v, __shfl_xor(v, 32));
      float mn = fmaxf(mrow[h], v);
      float alpha = __builtin_amdgcn_exp2f(mrow[h] - mn);
      mrow[h] = mn;
      lsum[h] *= alpha;
      #pragma unroll
      for (int ni = 0; ni < 4; ni++)
        #pragma unroll
        for (int jj = 0; jj < 4; jj++)
          o[ni][h][jj] *= alpha;
    }
    const float mn = mrow[h];
    char* hb = Pw + h*2560;
    float psum = 0.f;
    #pragma unroll
    for (int ni = 0; ni < 4; ni++){
      float p0 = __builtin_amdgcn_exp2f(s[ni][h][0] - mn);
      float p1 = __builtin_amdgcn_exp2f(s[ni][h][1] - mn);
      float p2 = __builtin_amdgcn_exp2f(s[ni][h][2] - mn);
      float p3 = __builtin_amdgcn_exp2f(s[ni][h][3] - mn);
      psum += (p0+p1) + (p2+p3);
      int tl = lr + 16*(((ni&1)<<1) | (lg>>1));
      int wb = ((ni>>1)<<2) | ((lg&1)<<1);
      *(u32*)(hb + tl*40 + wb*4)     = pack_bf2(p0, p1);
      *(u32*)(hb + tl*40 + wb*4 + 4) = pack_bf2(p2, p3);
    }
    lsum[h] += psum;
  };

  auto read_pb = [&](int h, short8& r0, short8& r1){
    const char* hb = Pw + h*2560 + (size_t)lane*40;
    union { u32 w[4]; short8 v; } a, b;
    a.w[0] = *(const u32*)(hb);      a.w[1] = *(const u32*)(hb + 4);
    a.w[2] = *(const u32*)(hb + 8);  a.w[3] = *(const u32*)(hb + 12);
    b.w[0] = *(const u32*)(hb + 16); b.w[1] = *(const u32*)(hb + 20);
    b.w[2] = *(const u32*)(hb + 24); b.w[3] = *(const u32*)(hb + 28);
    r0 = a.v; r1 = b.v;
  };

  int kvb = 0;

  #pragma unroll 1
  for (; kvb <= p; kvb++){
    const int c = kvb & 1;
    const int kv0 = kvb*64;
    asm volatile("s_waitcnt vmcnt(0)" ::: "memory");
    __builtin_amdgcn_s_barrier();
    if (kvb+1 < nkv) stageKV(kv0 + 64, c^1);

    const char* Kb = smem + c*16384;
    const char* Vb = Kb + 8192;

    f32x4 s[4][2] = {};
    __builtin_amdgcn_s_setprio(1);
    #pragma unroll
    for (int ni = 0; ni < 4; ni++){
      short8 k0 = *(const short8*)(Kb + (ni*16+lr)*128 + ((lg*16) ^ fswz));
      short8 k1 = *(const short8*)(Kb + (ni*16+lr)*128 + ((64 + lg*16) ^ fswz));
      #pragma unroll
      for (int h = 0; h < 2; h++){
        s[ni][h] = __builtin_amdgcn_mfma_f32_16x16x32_bf16(k0, bq[h][0], s[ni][h], 0,0,0);
        s[ni][h] = __builtin_amdgcn_mfma_f32_16x16x32_bf16(k1, bq[h][1], s[ni][h], 0,0,0);
      }
    }
    __builtin_amdgcn_s_setprio(0);

    softmax_pack(s, 0, false, kv0, qrow[0]);
    softmax_pack(s, 1, kvb == p, kv0, qrow[1]);

    short8 pb[2][2];
    read_pb(0, pb[0][0], pb[0][1]);
    read_pb(1, pb[1][0], pb[1][1]);

    __builtin_amdgcn_s_setprio(1);
    #pragma unroll
    for (int ni = 0; ni < 4; ni++){
      short8 v0 = *(const short8*)(Vb + (ni*16+lr)*128 + ((lg*16) ^ fswz));
      short8 v1 = *(const short8*)(Vb + (ni*16+lr)*128 + ((64 + lg*16) ^ fswz));
      #pragma unroll
      for (int h = 0; h < 2; h++){
        o[ni][h] = __builtin_amdgcn_mfma_f32_16x16x32_bf16(v0, pb[h][0], o[ni][h], 0,0,0);
        o[ni][h] = __builtin_amdgcn_mfma_f32_16x16x32_bf16(v1, pb[h][1], o[ni][h], 0,0,0);
      }
    }
    __builtin_amdgcn_s_setprio(0);
  }

  #pragma unroll 1
  for (; kvb < nkv; kvb++){
    const int c = kvb & 1;
    const int kv0 = kvb*64;
    asm volatile("s_waitcnt vmcnt(0)" ::: "memory");
    __builtin_amdgcn_s_barrier();
    if (kvb+1 < nkv) stageKV(kv0 + 64, c^1);

    const char* Kb = smem + c*16384;
    const char* Vb = Kb + 8192;

    f32x4 s[4][2];
    #pragma unroll
    for (int ni = 0; ni < 4; ni++) s[ni][0] = (f32x4){0.f,0.f,0.f,0.f};
    __builtin_amdgcn_s_setprio(1);
    #pragma unroll
    for (int ni = 0; ni < 4; ni++){
      short8 k0 = *(const short8*)(Kb + (ni*16+lr)*128 + ((lg*16) ^ fswz));
      short8 k1 = *(const short8*)(Kb + (ni*16+lr)*128 + ((64 + lg*16) ^ fswz));
      s[ni][0] = __builtin_amdgcn_mfma_f32_16x16x32_bf16(k0, bq[0][0], s[ni][0], 0,0,0);
      s[ni][0] = __builtin_amdgcn_mfma_f32_16x16x32_bf16(k1, bq[0][1], s[ni][0], 0,0,0);
    }
    __builtin_amdgcn_s_setprio(0);

    softmax_pack(s, 0, kvb == hi, kv0, qrow[0]);

    short8 pb0, pb1;
    read_pb(0, pb0, pb1);

    __builtin_amdgcn_s_setprio(1);
    #pragma unroll
    for (int ni = 0; ni < 4; ni++){
      short8 v0 = *(const short8*)(Vb + (ni*16+lr)*128 + ((lg*16) ^ fswz));
      short8 v1 = *(const short8*)(Vb + (ni*16+lr)*128 + ((64 + lg*16) ^ fswz));
      o[ni][0] = __builtin_amdgcn_mfma_f32_16x16x32_bf16(v0, pb0, o[ni][0], 0,0,0);
      o[ni][0] = __builtin_amdgcn_mfma_f32_16x16x32_bf16(v1, pb1, o[ni][0], 0,0,0);
    }
    __builtin_amdgcn_s_setprio(0);
  }

  #pragma unroll
  for (int h = 0; h < 2; h++){
    float ls = lsum[h];
    ls += __shfl_xor(ls, 16);
    ls += __shfl_xor(ls, 32);
    float inv = 1.0f / ls;
    u16* orow = aout + ((size_t)b_*SEQ + qrow[h])*D_MODEL + h_*HD;
    #pragma unroll
    for (int ni = 0; ni < 4; ni++){
      ushort4 w;
      w.x = f2bf(o[ni][h][0]*inv);
      w.y = f2bf(o[ni][h][1]*inv);
      w.z = f2bf(o[ni][h][2]*inv);
      w.w = f2bf(o[ni][h][3]*inv);
      *(ushort4*)(orow + ni*16 + lg*4) = w;
    }
  }
}

extern "C" void kernel_launch(void* const* d_in, const int* in_sizes, int n_in,
                              void* d_out, int out_size, void* d_ws, size_t ws_size,
                              hipStream_t stream)
{
  const float* x    = (const float*)d_in[0];
  const float* Wqkv = (const float*)d_in[1];
  const float* bqkv = (const float*)d_in[2];
  const float* Wout = (const float*)d_in[3];
  const float* bout = (const float*)d_in[4];
  float* out = (float*)d_out;
  char* ws = (char*)d_ws;

  // workspace layout (bytes)
  u16* x_bf   = (u16*)(ws + 0);          // 8192x768   bf16 = 12,582,912
  u16* wqkv_t = (u16*)(ws + 12582912);   // 2304x768   bf16 =  3,538,944
  u16* wout_t = (u16*)(ws + 16121856);   //  768x768   bf16 =  1,179,648
  u16* qb     = (u16*)(ws + 17301504);   // [48][2048][64]  = 12,582,912
  u16* kb     = (u16*)(ws + 29884416);   // [48][2048][64]  = 12,582,912
  u16* vtb    = (u16*)(ws + 42467328);   // [48][64][2048]  = 12,582,912
  u16* attnb  = (u16*)(ws + 55050240);   // 8192x768   bf16 = 12,582,912

  cast4_kernel<<<6144, 256, 0, stream>>>(x, x_bf, (BATCH*SEQ*D_MODEL)/4);
  transpose_cast_kernel<<<dim3(12, 36), 256, 0, stream>>>(Wqkv, wqkv_t, 768, 2304);
  transpose_cast_kernel<<<dim3(12, 12), 256, 0, stream>>>(Wout, wout_t, 768, 768);

  gemm_bf16<1><<<dim3(64, 18), 256, 0, stream>>>(x_bf, wqkv_t, bqkv, nullptr,
                                                 qb, kb, vtb, MROWS, 3*D_MODEL, D_MODEL);

  attn_kernel<<<768, 256, 0, stream>>>(qb, kb, vtb, attnb);

  gemm_bf16<0><<<dim3(64, 6), 256, 0, stream>>>(attnb, wout_t, bout, out,
                                                nullptr, nullptr, nullptr, MROWS, D_MODEL, D_MODEL);
}

// Round 12
// 133.027 us; speedup vs baseline: 1.3876x; 1.0376x over previous
//
#include <hip/hip_runtime.h>
#include <hip/hip_bf16.h>

// Problem constants
#define D_MODEL 768
#define NH 12
#define HD 64
#define BATCH 4
#define SEQ 2048
#define BHN (BATCH*NH)        // 48
#define MROWS (BATCH*SEQ)     // 8192

typedef unsigned short u16;
typedef unsigned int u32;
typedef __attribute__((ext_vector_type(8))) short short8;
typedef __attribute__((ext_vector_type(4))) float f32x4;

__device__ inline u16 f2bf(float f){
  union { __hip_bfloat16 h; u16 u; } cv; cv.h = __float2bfloat16(f); return cv.u;
}
__device__ inline u32 pack_bf2(float a, float b){
  return (u32)f2bf(a) | ((u32)f2bf(b) << 16);
}

// async global->LDS, 16B per lane. LDS dest = wave-uniform base + lane*16.
__device__ inline void async_copy16(const void* g, void* l){
  __builtin_amdgcn_global_load_lds(
      (const __attribute__((address_space(1))) void*)g,
      (__attribute__((address_space(3))) void*)l, 16, 0, 0);
}

// ---------------- fused prep: cast x (blocks 0..6143), transpose Wqkv
// (6144..6575), transpose Wout (6576..6719) ----------------
__global__ void prep_kernel(const float* __restrict__ x, u16* __restrict__ x_bf,
                            const float* __restrict__ wqkv, u16* __restrict__ wqkv_t,
                            const float* __restrict__ wout, u16* __restrict__ wout_t)
{
  __shared__ u16 tile[64][65];
  const int bid = blockIdx.x, tid = threadIdx.x;
  if (bid < 6144){
    int i = bid*256 + tid;
    const float4 v = ((const float4*)x)[i];
    ushort4 o;
    o.x = f2bf(v.x); o.y = f2bf(v.y); o.z = f2bf(v.z); o.w = f2bf(v.w);
    ((ushort4*)x_bf)[i] = o;
    return;
  }
  const float* w; u16* wt; int K, N, t;
  if (bid < 6576){ w = wqkv; wt = wqkv_t; K = 768; N = 2304; t = bid - 6144; }
  else           { w = wout; wt = wout_t; K = 768; N = 768;  t = bid - 6576; }
  int k0 = (t % 12)*64, n0 = (t / 12)*64;
  int c = tid & 63, r0 = tid >> 6;
  #pragma unroll
  for (int r = r0; r < 64; r += 4)
    tile[c][r] = f2bf(w[(size_t)(k0+r)*N + n0 + c]);
  __syncthreads();
  #pragma unroll
  for (int r = r0; r < 64; r += 4)
    wt[(size_t)(n0+r)*K + k0 + c] = tile[r][c];
}

// ---------------- bf16 GEMM (QKV): C[M,N] = A[M,K] @ Bt[N,K]^T ----------------
// 128x128 tile, BK=32, 2-buffer LDS (32KB, full residency), granule XOR-swizzle
// (conflicts=0). FROZEN structure (R11 verified).
__launch_bounds__(256)
__global__ void gemm_qkv(const u16* __restrict__ A, const u16* __restrict__ Bt,
                         const float* __restrict__ bias,
                         u16* __restrict__ oq, u16* __restrict__ ok, u16* __restrict__ ovt,
                         int M, int N, int K)
{
  __shared__ alignas(16) char smem[32768];   // 2 bufs x (A 8KB + B 8KB)
  const int tid = threadIdx.x, wave = tid>>6, lane = tid&63;
  const int lr = lane&15, lg = lane>>4;
  const int m0 = blockIdx.x*128, n0 = blockIdx.y*128;
  const int wr = (wave>>1)*64, wc = (wave&1)*64;
  f32x4 acc[4][4] = {};
  const int srow = wave*32 + (lane>>2);              // staging row (+i*16)
  const int schk = (lane&3) ^ ((lane>>3)&3);         // swizzled source granule
  const int fo   = ((lg ^ ((lr>>1)&3)) << 4);        // swizzled frag byte offset

  auto stage = [&](int kt, int buf){
    char* Ab = smem + buf*16384;
    char* Bb = Ab + 8192;
    #pragma unroll
    for (int i = 0; i < 2; i++){
      int r = srow + i*16;
      async_copy16(A  + (size_t)(m0 + r)*K + kt + schk*8, Ab + (wave*32 + i*16)*64);
      async_copy16(Bt + (size_t)(n0 + r)*K + kt + schk*8, Bb + (wave*32 + i*16)*64);
    }
  };

  const int NT = K >> 5;
  stage(0, 0);
  for (int t = 0; t < NT; t++){
    const int c = t & 1;
    asm volatile("s_waitcnt vmcnt(0)" ::: "memory");
    __builtin_amdgcn_s_barrier();
    if (t+1 < NT) stage((t+1)<<5, c^1);

    const char* Ac = smem + c*16384;
    const char* Bc = Ac + 8192;
    short8 a[4], b[4];
    #pragma unroll
    for (int mi = 0; mi < 4; mi++)
      a[mi] = *(const short8*)(Ac + (wr + mi*16 + lr)*64 + fo);
    #pragma unroll
    for (int ni = 0; ni < 4; ni++)
      b[ni] = *(const short8*)(Bc + (wc + ni*16 + lr)*64 + fo);
    #pragma unroll
    for (int mi = 0; mi < 4; mi++)
      #pragma unroll
      for (int ni = 0; ni < 4; ni++)
        acc[mi][ni] = __builtin_amdgcn_mfma_f32_16x16x32_bf16(a[mi], b[ni], acc[mi][ni], 0, 0, 0);
  }

  // epilogue: C row = (lane>>4)*4 + j, col = lane&15  [verified C/D layout]
  #pragma unroll
  for (int mi = 0; mi < 4; mi++)
  #pragma unroll
  for (int ni = 0; ni < 4; ni++)
  #pragma unroll
  for (int j = 0; j < 4; j++){
    int m = m0 + wr + mi*16 + lg*4 + j;
    int n = n0 + wc + ni*16 + lr;
    float v = acc[mi][ni][j] + bias[n];
    int b_ = m >> 11, s = m & 2047;
    int ty = (n >= 1536) ? 2 : (n >= 768 ? 1 : 0);
    int hn = n - ty*768;
    int h = hn >> 6, d = hn & 63;
    size_t base = (size_t)(b_*NH + h);
    if (ty == 0)      oq [(base*SEQ + s)*HD + d] = f2bf(v * 0.1803368801f); // fold 0.125*log2e into Q
    else if (ty == 1) ok [(base*SEQ + s)*HD + d] = f2bf(v);
    else              ovt[(base*HD + d)*SEQ + s] = f2bf(v);   // V stored transposed
  }
}

// ---------------- bf16 GEMM (out-proj): 64x128 tile for uniform 3 blocks/CU ----
// Same 2-phase + swizzle pattern as gemm_qkv; grid 128x6 = 768 blocks (zero
// load imbalance vs 384-block BM=128 version where half the CUs ran 2 blocks).
__launch_bounds__(256)
__global__ void gemm_out64(const u16* __restrict__ A, const u16* __restrict__ Bt,
                           const float* __restrict__ bias, float* __restrict__ outf,
                           int M, int N, int K)
{
  __shared__ alignas(16) char smem[24576];   // 2 bufs x (A 4KB + B 8KB)
  const int tid = threadIdx.x, wave = tid>>6, lane = tid&63;
  const int lr = lane&15, lg = lane>>4;
  const int m0 = blockIdx.x*64, n0 = blockIdx.y*128;
  const int wr = (wave>>1)*32, wc = (wave&1)*64;
  f32x4 acc[2][4] = {};
  const int srowB = wave*32 + (lane>>2);             // B staging row (+i*16)
  const int schk  = (lane&3) ^ ((lane>>3)&3);        // swizzled source granule (B)
  const int rowA  = tid >> 2;                        // A staging row (1 chunk/thread)
  const int schkA = (tid&3) ^ ((tid>>3)&3);          // swizzled source granule (A)
  const int fo    = ((lg ^ ((lr>>1)&3)) << 4);       // swizzled frag byte offset

  auto stage = [&](int kt, int buf){
    char* Ab = smem + buf*12288;
    char* Bb = Ab + 4096;
    async_copy16(A + (size_t)(m0 + rowA)*K + kt + schkA*8, Ab + (wave*16)*64);
    #pragma unroll
    for (int i = 0; i < 2; i++){
      int r = srowB + i*16;
      async_copy16(Bt + (size_t)(n0 + r)*K + kt + schk*8, Bb + (wave*32 + i*16)*64);
    }
  };

  const int NT = K >> 5;
  stage(0, 0);
  for (int t = 0; t < NT; t++){
    const int c = t & 1;
    asm volatile("s_waitcnt vmcnt(0)" ::: "memory");
    __builtin_amdgcn_s_barrier();
    if (t+1 < NT) stage((t+1)<<5, c^1);

    const char* Ac = smem + c*12288;
    const char* Bc = Ac + 4096;
    short8 a[2], b[4];
    #pragma unroll
    for (int mi = 0; mi < 2; mi++)
      a[mi] = *(const short8*)(Ac + (wr + mi*16 + lr)*64 + fo);
    #pragma unroll
    for (int ni = 0; ni < 4; ni++)
      b[ni] = *(const short8*)(Bc + (wc + ni*16 + lr)*64 + fo);
    #pragma unroll
    for (int mi = 0; mi < 2; mi++)
      #pragma unroll
      for (int ni = 0; ni < 4; ni++)
        acc[mi][ni] = __builtin_amdgcn_mfma_f32_16x16x32_bf16(a[mi], b[ni], acc[mi][ni], 0, 0, 0);
  }

  #pragma unroll
  for (int mi = 0; mi < 2; mi++)
  #pragma unroll
  for (int ni = 0; ni < 4; ni++)
  #pragma unroll
  for (int j = 0; j < 4; j++){
    int m = m0 + wr + mi*16 + lg*4 + j;
    int n = n0 + wc + ni*16 + lr;
    outf[(size_t)m*N + n] = acc[mi][ni][j] + bias[n];
  }
}

// ---------------- flash attention: merged causal pair-sweep (unchanged) ----------------
__launch_bounds__(256, 3)
__global__ void attn_kernel(const u16* __restrict__ q, const u16* __restrict__ k,
                            const u16* __restrict__ vt, u16* __restrict__ aout)
{
  __shared__ alignas(16) char smem[53248];
  const int b1 = blockIdx.x;                 // 0..767
  const int xcd = b1 & 7, grp = b1 >> 3;     // grp 0..95
  const int bh = xcd*6 + (grp >> 4);         // 6 heads per XCD (L2 locality)
  const int p  = grp & 15;                   // lo tile index 0..15
  const int hi = 31 - p;                     // hi tile index 16..31
  const int tid = threadIdx.x, wave = tid>>6, lane = tid&63;
  const int lr = lane&15, lg = lane>>4;
  const int b_ = bh / NH, h_ = bh % NH;
  const u16* qp = q  + (size_t)bh*SEQ*HD;
  const u16* kp = k  + (size_t)bh*SEQ*HD;
  const u16* vp = vt + (size_t)bh*HD*SEQ;
  char* Pw = smem + 32768 + wave*5120;
  const int fswz = (lr&7)<<4;
  const int c8s = (lane&7) ^ (lane>>3);
  const int nkv = hi + 1;

  auto stageKV = [&](int kv0, int buf){
    char* Kb = smem + buf*16384;
    char* Vb = Kb + 8192;
    #pragma unroll
    for (int r = 0; r < 2; r++){
      int row = wave*16 + r*8 + (lane>>3);
      async_copy16(kp + (size_t)(kv0 + row)*HD + c8s*8, Kb + (wave*16 + r*8)*128);
      async_copy16(vp + (size_t)row*SEQ + kv0 + c8s*8,  Vb + (wave*16 + r*8)*128);
    }
  };

  const int qrow[2] = { hi*64 + wave*16 + lr, p*64 + wave*16 + lr };

  short8 bq[2][2];
  #pragma unroll
  for (int h = 0; h < 2; h++)
    #pragma unroll
    for (int ks = 0; ks < 2; ks++)
      bq[h][ks] = *(const short8*)(qp + (size_t)qrow[h]*HD + ks*32 + lg*8);

  float mrow[2] = {-INFINITY, -INFINITY};
  float lsum[2] = {0.f, 0.f};
  f32x4 o[4][2] = {};

  stageKV(0, 0);

  auto softmax_pack = [&](f32x4 (&s)[4][2], int h, bool domask, int kv0, int qr){
    if (domask){
      #pragma unroll
      for (int ni = 0; ni < 4; ni++)
        #pragma unroll
        for (int jj = 0; jj < 4; jj++){
          int col = kv0 + ni*16 + lg*4 + jj;
          if (col > qr) s[ni][h][jj] = -1e30f;
        }
    }
    float v0 = fmaxf(fmaxf(s[0][h][0], s[0][h][1]), fmaxf(s[0][h][2], s[0][h][3]));
    float v1 = fmaxf(fmaxf(s[1][h][0], s[1][h][1]), fmaxf(s[1][h][2], s[1][h][3]));
    float v2 = fmaxf(fmaxf(s[2][h][0], s[2][h][1]), fmaxf(s[2][h][2], s[2][h][3]));
    float v3 = fmaxf(fmaxf(s[3][h][0], s[3][h][1]), fmaxf(s[3][h][2], s[3][h][3]));
    float vloc = fmaxf(fmaxf(v0, v1), fmaxf(v2, v3));
    if (!__all(vloc - mrow[h] <= 8.0f)){
      float v = fmaxf(vloc, __shfl_xor(vloc, 16));
      v = fmaxf(v, __shfl_xor(v, 32));
      float mn = fmaxf(mrow[h], v);
      float alpha = __builtin_amdgcn_exp2f(mrow[h] - mn);
      mrow[h] = mn;
      lsum[h] *= alpha;
      #pragma unroll
      for (int ni = 0; ni < 4; ni++)
        #pragma unroll
        for (int jj = 0; jj < 4; jj++)
          o[ni][h][jj] *= alpha;
    }
    const float mn = mrow[h];
    char* hb = Pw + h*2560;
    float psum = 0.f;
    #pragma unroll
    for (int ni = 0; ni < 4; ni++){
      float p0 = __builtin_amdgcn_exp2f(s[ni][h][0] - mn);
      float p1 = __builtin_amdgcn_exp2f(s[ni][h][1] - mn);
      float p2 = __builtin_amdgcn_exp2f(s[ni][h][2] - mn);
      float p3 = __builtin_amdgcn_exp2f(s[ni][h][3] - mn);
      psum += (p0+p1) + (p2+p3);
      int tl = lr + 16*(((ni&1)<<1) | (lg>>1));
      int wb = ((ni>>1)<<2) | ((lg&1)<<1);
      *(u32*)(hb + tl*40 + wb*4)     = pack_bf2(p0, p1);
      *(u32*)(hb + tl*40 + wb*4 + 4) = pack_bf2(p2, p3);
    }
    lsum[h] += psum;
  };

  auto read_pb = [&](int h, short8& r0, short8& r1){
    const char* hb = Pw + h*2560 + (size_t)lane*40;
    union { u32 w[4]; short8 v; } a, b;
    a.w[0] = *(const u32*)(hb);      a.w[1] = *(const u32*)(hb + 4);
    a.w[2] = *(const u32*)(hb + 8);  a.w[3] = *(const u32*)(hb + 12);
    b.w[0] = *(const u32*)(hb + 16); b.w[1] = *(const u32*)(hb + 20);
    b.w[2] = *(const u32*)(hb + 24); b.w[3] = *(const u32*)(hb + 28);
    r0 = a.v; r1 = b.v;
  };

  int kvb = 0;

  #pragma unroll 1
  for (; kvb <= p; kvb++){
    const int c = kvb & 1;
    const int kv0 = kvb*64;
    asm volatile("s_waitcnt vmcnt(0)" ::: "memory");
    __builtin_amdgcn_s_barrier();
    if (kvb+1 < nkv) stageKV(kv0 + 64, c^1);

    const char* Kb = smem + c*16384;
    const char* Vb = Kb + 8192;

    f32x4 s[4][2] = {};
    __builtin_amdgcn_s_setprio(1);
    #pragma unroll
    for (int ni = 0; ni < 4; ni++){
      short8 k0 = *(const short8*)(Kb + (ni*16+lr)*128 + ((lg*16) ^ fswz));
      short8 k1 = *(const short8*)(Kb + (ni*16+lr)*128 + ((64 + lg*16) ^ fswz));
      #pragma unroll
      for (int h = 0; h < 2; h++){
        s[ni][h] = __builtin_amdgcn_mfma_f32_16x16x32_bf16(k0, bq[h][0], s[ni][h], 0,0,0);
        s[ni][h] = __builtin_amdgcn_mfma_f32_16x16x32_bf16(k1, bq[h][1], s[ni][h], 0,0,0);
      }
    }
    __builtin_amdgcn_s_setprio(0);

    softmax_pack(s, 0, false, kv0, qrow[0]);
    softmax_pack(s, 1, kvb == p, kv0, qrow[1]);

    short8 pb[2][2];
    read_pb(0, pb[0][0], pb[0][1]);
    read_pb(1, pb[1][0], pb[1][1]);

    __builtin_amdgcn_s_setprio(1);
    #pragma unroll
    for (int ni = 0; ni < 4; ni++){
      short8 v0 = *(const short8*)(Vb + (ni*16+lr)*128 + ((lg*16) ^ fswz));
      short8 v1 = *(const short8*)(Vb + (ni*16+lr)*128 + ((64 + lg*16) ^ fswz));
      #pragma unroll
      for (int h = 0; h < 2; h++){
        o[ni][h] = __builtin_amdgcn_mfma_f32_16x16x32_bf16(v0, pb[h][0], o[ni][h], 0,0,0);
        o[ni][h] = __builtin_amdgcn_mfma_f32_16x16x32_bf16(v1, pb[h][1], o[ni][h], 0,0,0);
      }
    }
    __builtin_amdgcn_s_setprio(0);
  }

  #pragma unroll 1
  for (; kvb < nkv; kvb++){
    const int c = kvb & 1;
    const int kv0 = kvb*64;
    asm volatile("s_waitcnt vmcnt(0)" ::: "memory");
    __builtin_amdgcn_s_barrier();
    if (kvb+1 < nkv) stageKV(kv0 + 64, c^1);

    const char* Kb = smem + c*16384;
    const char* Vb = Kb + 8192;

    f32x4 s[4][2];
    #pragma unroll
    for (int ni = 0; ni < 4; ni++) s[ni][0] = (f32x4){0.f,0.f,0.f,0.f};
    __builtin_amdgcn_s_setprio(1);
    #pragma unroll
    for (int ni = 0; ni < 4; ni++){
      short8 k0 = *(const short8*)(Kb + (ni*16+lr)*128 + ((lg*16) ^ fswz));
      short8 k1 = *(const short8*)(Kb + (ni*16+lr)*128 + ((64 + lg*16) ^ fswz));
      s[ni][0] = __builtin_amdgcn_mfma_f32_16x16x32_bf16(k0, bq[0][0], s[ni][0], 0,0,0);
      s[ni][0] = __builtin_amdgcn_mfma_f32_16x16x32_bf16(k1, bq[0][1], s[ni][0], 0,0,0);
    }
    __builtin_amdgcn_s_setprio(0);

    softmax_pack(s, 0, kvb == hi, kv0, qrow[0]);

    short8 pb0, pb1;
    read_pb(0, pb0, pb1);

    __builtin_amdgcn_s_setprio(1);
    #pragma unroll
    for (int ni = 0; ni < 4; ni++){
      short8 v0 = *(const short8*)(Vb + (ni*16+lr)*128 + ((lg*16) ^ fswz));
      short8 v1 = *(const short8*)(Vb + (ni*16+lr)*128 + ((64 + lg*16) ^ fswz));
      o[ni][0] = __builtin_amdgcn_mfma_f32_16x16x32_bf16(v0, pb0, o[ni][0], 0,0,0);
      o[ni][0] = __builtin_amdgcn_mfma_f32_16x16x32_bf16(v1, pb1, o[ni][0], 0,0,0);
    }
    __builtin_amdgcn_s_setprio(0);
  }

  #pragma unroll
  for (int h = 0; h < 2; h++){
    float ls = lsum[h];
    ls += __shfl_xor(ls, 16);
    ls += __shfl_xor(ls, 32);
    float inv = 1.0f / ls;
    u16* orow = aout + ((size_t)b_*SEQ + qrow[h])*D_MODEL + h_*HD;
    #pragma unroll
    for (int ni = 0; ni < 4; ni++){
      ushort4 w;
      w.x = f2bf(o[ni][h][0]*inv);
      w.y = f2bf(o[ni][h][1]*inv);
      w.z = f2bf(o[ni][h][2]*inv);
      w.w = f2bf(o[ni][h][3]*inv);
      *(ushort4*)(orow + ni*16 + lg*4) = w;
    }
  }
}

extern "C" void kernel_launch(void* const* d_in, const int* in_sizes, int n_in,
                              void* d_out, int out_size, void* d_ws, size_t ws_size,
                              hipStream_t stream)
{
  const float* x    = (const float*)d_in[0];
  const float* Wqkv = (const float*)d_in[1];
  const float* bqkv = (const float*)d_in[2];
  const float* Wout = (const float*)d_in[3];
  const float* bout = (const float*)d_in[4];
  float* out = (float*)d_out;
  char* ws = (char*)d_ws;

  // workspace layout (bytes)
  u16* x_bf   = (u16*)(ws + 0);          // 8192x768   bf16 = 12,582,912
  u16* wqkv_t = (u16*)(ws + 12582912);   // 2304x768   bf16 =  3,538,944
  u16* wout_t = (u16*)(ws + 16121856);   //  768x768   bf16 =  1,179,648
  u16* qb     = (u16*)(ws + 17301504);   // [48][2048][64]  = 12,582,912
  u16* kb     = (u16*)(ws + 29884416);   // [48][2048][64]  = 12,582,912
  u16* vtb    = (u16*)(ws + 42467328);   // [48][64][2048]  = 12,582,912
  u16* attnb  = (u16*)(ws + 55050240);   // 8192x768   bf16 = 12,582,912

  prep_kernel<<<6720, 256, 0, stream>>>(x, x_bf, Wqkv, wqkv_t, Wout, wout_t);

  gemm_qkv<<<dim3(64, 18), 256, 0, stream>>>(x_bf, wqkv_t, bqkv,
                                             qb, kb, vtb, MROWS, 3*D_MODEL, D_MODEL);

  attn_kernel<<<768, 256, 0, stream>>>(qb, kb, vtb, attnb);

  gemm_out64<<<dim3(128, 6), 256, 0, stream>>>(attnb, wout_t, bout, out,
                                               MROWS, D_MODEL, D_MODEL);
}

// Round 13
// 126.703 us; speedup vs baseline: 1.4568x; 1.0499x over previous
//
#include <hip/hip_runtime.h>
#include <hip/hip_bf16.h>

// Problem constants
#define D_MODEL 768
#define NH 12
#define HD 64
#define BATCH 4
#define SEQ 2048
#define BHN (BATCH*NH)        // 48
#define MROWS (BATCH*SEQ)     // 8192

typedef unsigned short u16;
typedef unsigned int u32;
typedef __attribute__((ext_vector_type(8))) short short8;
typedef __attribute__((ext_vector_type(4))) float f32x4;

__device__ inline u16 f2bf(float f){
  union { __hip_bfloat16 h; u16 u; } cv; cv.h = __float2bfloat16(f); return cv.u;
}
__device__ inline u32 pack_bf2(float a, float b){
  return (u32)f2bf(a) | ((u32)f2bf(b) << 16);
}

// async global->LDS, 16B per lane. LDS dest = wave-uniform base + lane*16.
__device__ inline void async_copy16(const void* g, void* l){
  __builtin_amdgcn_global_load_lds(
      (const __attribute__((address_space(1))) void*)g,
      (__attribute__((address_space(3))) void*)l, 16, 0, 0);
}

// ---------------- fused prep: cast x (blocks 0..6143), transpose Wqkv
// (6144..6575), transpose Wout (6576..6719) ----------------
__global__ void prep_kernel(const float* __restrict__ x, u16* __restrict__ x_bf,
                            const float* __restrict__ wqkv, u16* __restrict__ wqkv_t,
                            const float* __restrict__ wout, u16* __restrict__ wout_t)
{
  __shared__ u16 tile[64][65];
  const int bid = blockIdx.x, tid = threadIdx.x;
  if (bid < 6144){
    int i = bid*256 + tid;
    const float4 v = ((const float4*)x)[i];
    ushort4 o;
    o.x = f2bf(v.x); o.y = f2bf(v.y); o.z = f2bf(v.z); o.w = f2bf(v.w);
    ((ushort4*)x_bf)[i] = o;
    return;
  }
  const float* w; u16* wt; int K, N, t;
  if (bid < 6576){ w = wqkv; wt = wqkv_t; K = 768; N = 2304; t = bid - 6144; }
  else           { w = wout; wt = wout_t; K = 768; N = 768;  t = bid - 6576; }
  int k0 = (t % 12)*64, n0 = (t / 12)*64;
  int c = tid & 63, r0 = tid >> 6;
  #pragma unroll
  for (int r = r0; r < 64; r += 4)
    tile[c][r] = f2bf(w[(size_t)(k0+r)*N + n0 + c]);
  __syncthreads();
  #pragma unroll
  for (int r = r0; r < 64; r += 4)
    wt[(size_t)(n0+r)*K + k0 + c] = tile[r][c];
}

// ---------------- bf16 GEMM (QKV): 128x192 tile, BK=32 ----------------
// Same frozen 2-phase + granule-swizzle template as R11/R12, BN widened to 192:
// 24 MFMA + 10 ds_read_b128 per K-step (amortizes the fixed drain/barrier cost
// over 1.5x more compute), grid 64x12 = 768 blocks = 3/CU exactly uniform
// (LDS 40KB -> 4/CU capacity; launch_bounds(256,3) caps VGPR <= ~170).
// 768 % 192 == 0 so tiles never straddle the Q/K/V boundary.
__launch_bounds__(256, 3)
__global__ void gemm_qkv(const u16* __restrict__ A, const u16* __restrict__ Bt,
                         const float* __restrict__ bias,
                         u16* __restrict__ oq, u16* __restrict__ ok, u16* __restrict__ ovt,
                         int M, int N, int K)
{
  __shared__ alignas(16) char smem[40960];   // 2 bufs x (A 8KB + B 12KB)
  const int tid = threadIdx.x, wave = tid>>6, lane = tid&63;
  const int lr = lane&15, lg = lane>>4;
  const int m0 = blockIdx.x*128, n0 = blockIdx.y*192;
  const int wr = (wave>>1)*64, wc = (wave&1)*96;
  f32x4 acc[4][6] = {};
  const int srowA = wave*32 + (lane>>2);             // A staging row (+i*16)
  const int srowB = wave*16 + (lane>>2);             // B staging row (+i*64)
  const int schk = (lane&3) ^ ((lane>>3)&3);         // swizzled source granule
  const int fo   = ((lg ^ ((lr>>1)&3)) << 4);        // swizzled frag byte offset

  auto stage = [&](int kt, int buf){
    char* Ab = smem + buf*20480;
    char* Bb = Ab + 8192;
    #pragma unroll
    for (int i = 0; i < 2; i++){
      int r = srowA + i*16;
      async_copy16(A + (size_t)(m0 + r)*K + kt + schk*8, Ab + (wave*32 + i*16)*64);
    }
    #pragma unroll
    for (int i = 0; i < 3; i++){
      int r = srowB + i*64;
      async_copy16(Bt + (size_t)(n0 + r)*K + kt + schk*8, Bb + i*4096 + wave*1024);
    }
  };

  const int NT = K >> 5;
  stage(0, 0);
  for (int t = 0; t < NT; t++){
    const int c = t & 1;
    asm volatile("s_waitcnt vmcnt(0)" ::: "memory");
    __builtin_amdgcn_s_barrier();
    if (t+1 < NT) stage((t+1)<<5, c^1);

    const char* Ac = smem + c*20480;
    const char* Bc = Ac + 8192;
    short8 a[4], b[6];
    #pragma unroll
    for (int mi = 0; mi < 4; mi++)
      a[mi] = *(const short8*)(Ac + (wr + mi*16 + lr)*64 + fo);
    #pragma unroll
    for (int ni = 0; ni < 6; ni++)
      b[ni] = *(const short8*)(Bc + (wc + ni*16 + lr)*64 + fo);
    #pragma unroll
    for (int mi = 0; mi < 4; mi++)
      #pragma unroll
      for (int ni = 0; ni < 6; ni++)
        acc[mi][ni] = __builtin_amdgcn_mfma_f32_16x16x32_bf16(a[mi], b[ni], acc[mi][ni], 0, 0, 0);
  }

  // epilogue: C row = (lane>>4)*4 + j, col = lane&15  [verified C/D layout]
  #pragma unroll
  for (int mi = 0; mi < 4; mi++)
  #pragma unroll
  for (int ni = 0; ni < 6; ni++)
  #pragma unroll
  for (int j = 0; j < 4; j++){
    int m = m0 + wr + mi*16 + lg*4 + j;
    int n = n0 + wc + ni*16 + lr;
    float v = acc[mi][ni][j] + bias[n];
    int b_ = m >> 11, s = m & 2047;
    int ty = (n >= 1536) ? 2 : (n >= 768 ? 1 : 0);
    int hn = n - ty*768;
    int h = hn >> 6, d = hn & 63;
    size_t base = (size_t)(b_*NH + h);
    if (ty == 0)      oq [(base*SEQ + s)*HD + d] = f2bf(v * 0.1803368801f); // fold 0.125*log2e into Q
    else if (ty == 1) ok [(base*SEQ + s)*HD + d] = f2bf(v);
    else              ovt[(base*HD + d)*SEQ + s] = f2bf(v);   // V stored transposed
  }
}

// ---------------- bf16 GEMM (out-proj): 64x128 tile, uniform 3 blocks/CU ----
__launch_bounds__(256)
__global__ void gemm_out64(const u16* __restrict__ A, const u16* __restrict__ Bt,
                           const float* __restrict__ bias, float* __restrict__ outf,
                           int M, int N, int K)
{
  __shared__ alignas(16) char smem[24576];   // 2 bufs x (A 4KB + B 8KB)
  const int tid = threadIdx.x, wave = tid>>6, lane = tid&63;
  const int lr = lane&15, lg = lane>>4;
  const int m0 = blockIdx.x*64, n0 = blockIdx.y*128;
  const int wr = (wave>>1)*32, wc = (wave&1)*64;
  f32x4 acc[2][4] = {};
  const int srowB = wave*32 + (lane>>2);             // B staging row (+i*16)
  const int schk  = (lane&3) ^ ((lane>>3)&3);        // swizzled source granule (B)
  const int rowA  = tid >> 2;                        // A staging row (1 chunk/thread)
  const int schkA = (tid&3) ^ ((tid>>3)&3);          // swizzled source granule (A)
  const int fo    = ((lg ^ ((lr>>1)&3)) << 4);       // swizzled frag byte offset

  auto stage = [&](int kt, int buf){
    char* Ab = smem + buf*12288;
    char* Bb = Ab + 4096;
    async_copy16(A + (size_t)(m0 + rowA)*K + kt + schkA*8, Ab + (wave*16)*64);
    #pragma unroll
    for (int i = 0; i < 2; i++){
      int r = srowB + i*16;
      async_copy16(Bt + (size_t)(n0 + r)*K + kt + schk*8, Bb + (wave*32 + i*16)*64);
    }
  };

  const int NT = K >> 5;
  stage(0, 0);
  for (int t = 0; t < NT; t++){
    const int c = t & 1;
    asm volatile("s_waitcnt vmcnt(0)" ::: "memory");
    __builtin_amdgcn_s_barrier();
    if (t+1 < NT) stage((t+1)<<5, c^1);

    const char* Ac = smem + c*12288;
    const char* Bc = Ac + 4096;
    short8 a[2], b[4];
    #pragma unroll
    for (int mi = 0; mi < 2; mi++)
      a[mi] = *(const short8*)(Ac + (wr + mi*16 + lr)*64 + fo);
    #pragma unroll
    for (int ni = 0; ni < 4; ni++)
      b[ni] = *(const short8*)(Bc + (wc + ni*16 + lr)*64 + fo);
    #pragma unroll
    for (int mi = 0; mi < 2; mi++)
      #pragma unroll
      for (int ni = 0; ni < 4; ni++)
        acc[mi][ni] = __builtin_amdgcn_mfma_f32_16x16x32_bf16(a[mi], b[ni], acc[mi][ni], 0, 0, 0);
  }

  #pragma unroll
  for (int mi = 0; mi < 2; mi++)
  #pragma unroll
  for (int ni = 0; ni < 4; ni++)
  #pragma unroll
  for (int j = 0; j < 4; j++){
    int m = m0 + wr + mi*16 + lg*4 + j;
    int n = n0 + wc + ni*16 + lr;
    outf[(size_t)m*N + n] = acc[mi][ni][j] + bias[n];
  }
}

// ---------------- flash attention: merged causal pair-sweep (unchanged) ----------------
__launch_bounds__(256, 3)
__global__ void attn_kernel(const u16* __restrict__ q, const u16* __restrict__ k,
                            const u16* __restrict__ vt, u16* __restrict__ aout)
{
  __shared__ alignas(16) char smem[53248];
  const int b1 = blockIdx.x;                 // 0..767
  const int xcd = b1 & 7, grp = b1 >> 3;     // grp 0..95
  const int bh = xcd*6 + (grp >> 4);         // 6 heads per XCD (L2 locality)
  const int p  = grp & 15;                   // lo tile index 0..15
  const int hi = 31 - p;                     // hi tile index 16..31
  const int tid = threadIdx.x, wave = tid>>6, lane = tid&63;
  const int lr = lane&15, lg = lane>>4;
  const int b_ = bh / NH, h_ = bh % NH;
  const u16* qp = q  + (size_t)bh*SEQ*HD;
  const u16* kp = k  + (size_t)bh*SEQ*HD;
  const u16* vp = vt + (size_t)bh*HD*SEQ;
  char* Pw = smem + 32768 + wave*5120;
  const int fswz = (lr&7)<<4;
  const int c8s = (lane&7) ^ (lane>>3);
  const int nkv = hi + 1;

  auto stageKV = [&](int kv0, int buf){
    char* Kb = smem + buf*16384;
    char* Vb = Kb + 8192;
    #pragma unroll
    for (int r = 0; r < 2; r++){
      int row = wave*16 + r*8 + (lane>>3);
      async_copy16(kp + (size_t)(kv0 + row)*HD + c8s*8, Kb + (wave*16 + r*8)*128);
      async_copy16(vp + (size_t)row*SEQ + kv0 + c8s*8,  Vb + (wave*16 + r*8)*128);
    }
  };

  const int qrow[2] = { hi*64 + wave*16 + lr, p*64 + wave*16 + lr };

  short8 bq[2][2];
  #pragma unroll
  for (int h = 0; h < 2; h++)
    #pragma unroll
    for (int ks = 0; ks < 2; ks++)
      bq[h][ks] = *(const short8*)(qp + (size_t)qrow[h]*HD + ks*32 + lg*8);

  float mrow[2] = {-INFINITY, -INFINITY};
  float lsum[2] = {0.f, 0.f};
  f32x4 o[4][2] = {};

  stageKV(0, 0);

  auto softmax_pack = [&](f32x4 (&s)[4][2], int h, bool domask, int kv0, int qr){
    if (domask){
      #pragma unroll
      for (int ni = 0; ni < 4; ni++)
        #pragma unroll
        for (int jj = 0; jj < 4; jj++){
          int col = kv0 + ni*16 + lg*4 + jj;
          if (col > qr) s[ni][h][jj] = -1e30f;
        }
    }
    float v0 = fmaxf(fmaxf(s[0][h][0], s[0][h][1]), fmaxf(s[0][h][2], s[0][h][3]));
    float v1 = fmaxf(fmaxf(s[1][h][0], s[1][h][1]), fmaxf(s[1][h][2], s[1][h][3]));
    float v2 = fmaxf(fmaxf(s[2][h][0], s[2][h][1]), fmaxf(s[2][h][2], s[2][h][3]));
    float v3 = fmaxf(fmaxf(s[3][h][0], s[3][h][1]), fmaxf(s[3][h][2], s[3][h][3]));
    float vloc = fmaxf(fmaxf(v0, v1), fmaxf(v2, v3));
    if (!__all(vloc - mrow[h] <= 8.0f)){
      float v = fmaxf(vloc, __shfl_xor(vloc, 16));
      v = fmaxf(v, __shfl_xor(v, 32));
      float mn = fmaxf(mrow[h], v);
      float alpha = __builtin_amdgcn_exp2f(mrow[h] - mn);
      mrow[h] = mn;
      lsum[h] *= alpha;
      #pragma unroll
      for (int ni = 0; ni < 4; ni++)
        #pragma unroll
        for (int jj = 0; jj < 4; jj++)
          o[ni][h][jj] *= alpha;
    }
    const float mn = mrow[h];
    char* hb = Pw + h*2560;
    float psum = 0.f;
    #pragma unroll
    for (int ni = 0; ni < 4; ni++){
      float p0 = __builtin_amdgcn_exp2f(s[ni][h][0] - mn);
      float p1 = __builtin_amdgcn_exp2f(s[ni][h][1] - mn);
      float p2 = __builtin_amdgcn_exp2f(s[ni][h][2] - mn);
      float p3 = __builtin_amdgcn_exp2f(s[ni][h][3] - mn);
      psum += (p0+p1) + (p2+p3);
      int tl = lr + 16*(((ni&1)<<1) | (lg>>1));
      int wb = ((ni>>1)<<2) | ((lg&1)<<1);
      *(u32*)(hb + tl*40 + wb*4)     = pack_bf2(p0, p1);
      *(u32*)(hb + tl*40 + wb*4 + 4) = pack_bf2(p2, p3);
    }
    lsum[h] += psum;
  };

  auto read_pb = [&](int h, short8& r0, short8& r1){
    const char* hb = Pw + h*2560 + (size_t)lane*40;
    union { u32 w[4]; short8 v; } a, b;
    a.w[0] = *(const u32*)(hb);      a.w[1] = *(const u32*)(hb + 4);
    a.w[2] = *(const u32*)(hb + 8);  a.w[3] = *(const u32*)(hb + 12);
    b.w[0] = *(const u32*)(hb + 16); b.w[1] = *(const u32*)(hb + 20);
    b.w[2] = *(const u32*)(hb + 24); b.w[3] = *(const u32*)(hb + 28);
    r0 = a.v; r1 = b.v;
  };

  int kvb = 0;

  #pragma unroll 1
  for (; kvb <= p; kvb++){
    const int c = kvb & 1;
    const int kv0 = kvb*64;
    asm volatile("s_waitcnt vmcnt(0)" ::: "memory");
    __builtin_amdgcn_s_barrier();
    if (kvb+1 < nkv) stageKV(kv0 + 64, c^1);

    const char* Kb = smem + c*16384;
    const char* Vb = Kb + 8192;

    f32x4 s[4][2] = {};
    __builtin_amdgcn_s_setprio(1);
    #pragma unroll
    for (int ni = 0; ni < 4; ni++){
      short8 k0 = *(const short8*)(Kb + (ni*16+lr)*128 + ((lg*16) ^ fswz));
      short8 k1 = *(const short8*)(Kb + (ni*16+lr)*128 + ((64 + lg*16) ^ fswz));
      #pragma unroll
      for (int h = 0; h < 2; h++){
        s[ni][h] = __builtin_amdgcn_mfma_f32_16x16x32_bf16(k0, bq[h][0], s[ni][h], 0,0,0);
        s[ni][h] = __builtin_amdgcn_mfma_f32_16x16x32_bf16(k1, bq[h][1], s[ni][h], 0,0,0);
      }
    }
    __builtin_amdgcn_s_setprio(0);

    softmax_pack(s, 0, false, kv0, qrow[0]);
    softmax_pack(s, 1, kvb == p, kv0, qrow[1]);

    short8 pb[2][2];
    read_pb(0, pb[0][0], pb[0][1]);
    read_pb(1, pb[1][0], pb[1][1]);

    __builtin_amdgcn_s_setprio(1);
    #pragma unroll
    for (int ni = 0; ni < 4; ni++){
      short8 v0 = *(const short8*)(Vb + (ni*16+lr)*128 + ((lg*16) ^ fswz));
      short8 v1 = *(const short8*)(Vb + (ni*16+lr)*128 + ((64 + lg*16) ^ fswz));
      #pragma unroll
      for (int h = 0; h < 2; h++){
        o[ni][h] = __builtin_amdgcn_mfma_f32_16x16x32_bf16(v0, pb[h][0], o[ni][h], 0,0,0);
        o[ni][h] = __builtin_amdgcn_mfma_f32_16x16x32_bf16(v1, pb[h][1], o[ni][h], 0,0,0);
      }
    }
    __builtin_amdgcn_s_setprio(0);
  }

  #pragma unroll 1
  for (; kvb < nkv; kvb++){
    const int c = kvb & 1;
    const int kv0 = kvb*64;
    asm volatile("s_waitcnt vmcnt(0)" ::: "memory");
    __builtin_amdgcn_s_barrier();
    if (kvb+1 < nkv) stageKV(kv0 + 64, c^1);

    const char* Kb = smem + c*16384;
    const char* Vb = Kb + 8192;

    f32x4 s[4][2];
    #pragma unroll
    for (int ni = 0; ni < 4; ni++) s[ni][0] = (f32x4){0.f,0.f,0.f,0.f};
    __builtin_amdgcn_s_setprio(1);
    #pragma unroll
    for (int ni = 0; ni < 4; ni++){
      short8 k0 = *(const short8*)(Kb + (ni*16+lr)*128 + ((lg*16) ^ fswz));
      short8 k1 = *(const short8*)(Kb + (ni*16+lr)*128 + ((64 + lg*16) ^ fswz));
      s[ni][0] = __builtin_amdgcn_mfma_f32_16x16x32_bf16(k0, bq[0][0], s[ni][0], 0,0,0);
      s[ni][0] = __builtin_amdgcn_mfma_f32_16x16x32_bf16(k1, bq[0][1], s[ni][0], 0,0,0);
    }
    __builtin_amdgcn_s_setprio(0);

    softmax_pack(s, 0, kvb == hi, kv0, qrow[0]);

    short8 pb0, pb1;
    read_pb(0, pb0, pb1);

    __builtin_amdgcn_s_setprio(1);
    #pragma unroll
    for (int ni = 0; ni < 4; ni++){
      short8 v0 = *(const short8*)(Vb + (ni*16+lr)*128 + ((lg*16) ^ fswz));
      short8 v1 = *(const short8*)(Vb + (ni*16+lr)*128 + ((64 + lg*16) ^ fswz));
      o[ni][0] = __builtin_amdgcn_mfma_f32_16x16x32_bf16(v0, pb0, o[ni][0], 0,0,0);
      o[ni][0] = __builtin_amdgcn_mfma_f32_16x16x32_bf16(v1, pb1, o[ni][0], 0,0,0);
    }
    __builtin_amdgcn_s_setprio(0);
  }

  #pragma unroll
  for (int h = 0; h < 2; h++){
    float ls = lsum[h];
    ls += __shfl_xor(ls, 16);
    ls += __shfl_xor(ls, 32);
    float inv = 1.0f / ls;
    u16* orow = aout + ((size_t)b_*SEQ + qrow[h])*D_MODEL + h_*HD;
    #pragma unroll
    for (int ni = 0; ni < 4; ni++){
      ushort4 w;
      w.x = f2bf(o[ni][h][0]*inv);
      w.y = f2bf(o[ni][h][1]*inv);
      w.z = f2bf(o[ni][h][2]*inv);
      w.w = f2bf(o[ni][h][3]*inv);
      *(ushort4*)(orow + ni*16 + lg*4) = w;
    }
  }
}

extern "C" void kernel_launch(void* const* d_in, const int* in_sizes, int n_in,
                              void* d_out, int out_size, void* d_ws, size_t ws_size,
                              hipStream_t stream)
{
  const float* x    = (const float*)d_in[0];
  const float* Wqkv = (const float*)d_in[1];
  const float* bqkv = (const float*)d_in[2];
  const float* Wout = (const float*)d_in[3];
  const float* bout = (const float*)d_in[4];
  float* out = (float*)d_out;
  char* ws = (char*)d_ws;

  // workspace layout (bytes)
  u16* x_bf   = (u16*)(ws + 0);          // 8192x768   bf16 = 12,582,912
  u16* wqkv_t = (u16*)(ws + 12582912);   // 2304x768   bf16 =  3,538,944
  u16* wout_t = (u16*)(ws + 16121856);   //  768x768   bf16 =  1,179,648
  u16* qb     = (u16*)(ws + 17301504);   // [48][2048][64]  = 12,582,912
  u16* kb     = (u16*)(ws + 29884416);   // [48][2048][64]  = 12,582,912
  u16* vtb    = (u16*)(ws + 42467328);   // [48][64][2048]  = 12,582,912
  u16* attnb  = (u16*)(ws + 55050240);   // 8192x768   bf16 = 12,582,912

  prep_kernel<<<6720, 256, 0, stream>>>(x, x_bf, Wqkv, wqkv_t, Wout, wout_t);

  gemm_qkv<<<dim3(64, 12), 256, 0, stream>>>(x_bf, wqkv_t, bqkv,
                                             qb, kb, vtb, MROWS, 3*D_MODEL, D_MODEL);

  attn_kernel<<<768, 256, 0, stream>>>(qb, kb, vtb, attnb);

  gemm_out64<<<dim3(128, 6), 256, 0, stream>>>(attnb, wout_t, bout, out,
                                               MROWS, D_MODEL, D_MODEL);
}

// Round 15
// 126.230 us; speedup vs baseline: 1.4623x; 1.0037x over previous
//
#include <hip/hip_runtime.h>
#include <hip/hip_bf16.h>

// Problem constants
#define D_MODEL 768
#define NH 12
#define HD 64
#define BATCH 4
#define SEQ 2048
#define BHN (BATCH*NH)        // 48
#define MROWS (BATCH*SEQ)     // 8192

typedef unsigned short u16;
typedef unsigned int u32;
typedef __attribute__((ext_vector_type(8))) short short8;
typedef __attribute__((ext_vector_type(4))) float f32x4;

__device__ inline u16 f2bf(float f){
  union { __hip_bfloat16 h; u16 u; } cv; cv.h = __float2bfloat16(f); return cv.u;
}
__device__ inline u32 pack_bf2(float a, float b){
  return (u32)f2bf(a) | ((u32)f2bf(b) << 16);
}

// async global->LDS, 16B per lane. LDS dest = wave-uniform base + lane*16.
__device__ inline void async_copy16(const void* g, void* l){
  __builtin_amdgcn_global_load_lds(
      (const __attribute__((address_space(1))) void*)g,
      (__attribute__((address_space(3))) void*)l, 16, 0, 0);
}

// ---------------- fused prep: cast x (blocks 0..6143), transpose Wqkv
// (6144..6575), transpose Wout (6576..6719) ----------------
__global__ void prep_kernel(const float* __restrict__ x, u16* __restrict__ x_bf,
                            const float* __restrict__ wqkv, u16* __restrict__ wqkv_t,
                            const float* __restrict__ wout, u16* __restrict__ wout_t)
{
  __shared__ u16 tile[64][65];
  const int bid = blockIdx.x, tid = threadIdx.x;
  if (bid < 6144){
    int i = bid*256 + tid;
    const float4 v = ((const float4*)x)[i];
    ushort4 o;
    o.x = f2bf(v.x); o.y = f2bf(v.y); o.z = f2bf(v.z); o.w = f2bf(v.w);
    ((ushort4*)x_bf)[i] = o;
    return;
  }
  const float* w; u16* wt; int K, N, t;
  if (bid < 6576){ w = wqkv; wt = wqkv_t; K = 768; N = 2304; t = bid - 6144; }
  else           { w = wout; wt = wout_t; K = 768; N = 768;  t = bid - 6576; }
  int k0 = (t % 12)*64, n0 = (t / 12)*64;
  int c = tid & 63, r0 = tid >> 6;
  #pragma unroll
  for (int r = r0; r < 64; r += 4)
    tile[c][r] = f2bf(w[(size_t)(k0+r)*N + n0 + c]);
  __syncthreads();
  #pragma unroll
  for (int r = r0; r < 64; r += 4)
    wt[(size_t)(n0+r)*K + k0 + c] = tile[r][c];
}

// ---------------- bf16 GEMM (QKV): 128x192 tile, BK=32 (frozen, R13) ----------------
__launch_bounds__(256, 3)
__global__ void gemm_qkv(const u16* __restrict__ A, const u16* __restrict__ Bt,
                         const float* __restrict__ bias,
                         u16* __restrict__ oq, u16* __restrict__ ok, u16* __restrict__ ovt,
                         int M, int N, int K)
{
  __shared__ alignas(16) char smem[40960];   // 2 bufs x (A 8KB + B 12KB)
  const int tid = threadIdx.x, wave = tid>>6, lane = tid&63;
  const int lr = lane&15, lg = lane>>4;
  const int m0 = blockIdx.x*128, n0 = blockIdx.y*192;
  const int wr = (wave>>1)*64, wc = (wave&1)*96;
  f32x4 acc[4][6] = {};
  const int srowA = wave*32 + (lane>>2);             // A staging row (+i*16)
  const int srowB = wave*16 + (lane>>2);             // B staging row (+i*64)
  const int schk = (lane&3) ^ ((lane>>3)&3);         // swizzled source granule
  const int fo   = ((lg ^ ((lr>>1)&3)) << 4);        // swizzled frag byte offset

  auto stage = [&](int kt, int buf){
    char* Ab = smem + buf*20480;
    char* Bb = Ab + 8192;
    #pragma unroll
    for (int i = 0; i < 2; i++){
      int r = srowA + i*16;
      async_copy16(A + (size_t)(m0 + r)*K + kt + schk*8, Ab + (wave*32 + i*16)*64);
    }
    #pragma unroll
    for (int i = 0; i < 3; i++){
      int r = srowB + i*64;
      async_copy16(Bt + (size_t)(n0 + r)*K + kt + schk*8, Bb + i*4096 + wave*1024);
    }
  };

  const int NT = K >> 5;
  stage(0, 0);
  for (int t = 0; t < NT; t++){
    const int c = t & 1;
    asm volatile("s_waitcnt vmcnt(0)" ::: "memory");
    __builtin_amdgcn_s_barrier();
    if (t+1 < NT) stage((t+1)<<5, c^1);

    const char* Ac = smem + c*20480;
    const char* Bc = Ac + 8192;
    short8 a[4], b[6];
    #pragma unroll
    for (int mi = 0; mi < 4; mi++)
      a[mi] = *(const short8*)(Ac + (wr + mi*16 + lr)*64 + fo);
    #pragma unroll
    for (int ni = 0; ni < 6; ni++)
      b[ni] = *(const short8*)(Bc + (wc + ni*16 + lr)*64 + fo);
    #pragma unroll
    for (int mi = 0; mi < 4; mi++)
      #pragma unroll
      for (int ni = 0; ni < 6; ni++)
        acc[mi][ni] = __builtin_amdgcn_mfma_f32_16x16x32_bf16(a[mi], b[ni], acc[mi][ni], 0, 0, 0);
  }

  // epilogue: C row = (lane>>4)*4 + j, col = lane&15  [verified C/D layout]
  #pragma unroll
  for (int mi = 0; mi < 4; mi++)
  #pragma unroll
  for (int ni = 0; ni < 6; ni++)
  #pragma unroll
  for (int j = 0; j < 4; j++){
    int m = m0 + wr + mi*16 + lg*4 + j;
    int n = n0 + wc + ni*16 + lr;
    float v = acc[mi][ni][j] + bias[n];
    int b_ = m >> 11, s = m & 2047;
    int ty = (n >= 1536) ? 2 : (n >= 768 ? 1 : 0);
    int hn = n - ty*768;
    int h = hn >> 6, d = hn & 63;
    size_t base = (size_t)(b_*NH + h);
    if (ty == 0)      oq [(base*SEQ + s)*HD + d] = f2bf(v * 0.1803368801f); // fold 0.125*log2e into Q
    else if (ty == 1) ok [(base*SEQ + s)*HD + d] = f2bf(v);
    else              ovt[(base*HD + d)*SEQ + s] = f2bf(v);   // V stored transposed
  }
}

// ---------------- bf16 GEMM (out-proj): 64x128 tile, uniform 3 blocks/CU ----
__launch_bounds__(256)
__global__ void gemm_out64(const u16* __restrict__ A, const u16* __restrict__ Bt,
                           const float* __restrict__ bias, float* __restrict__ outf,
                           int M, int N, int K)
{
  __shared__ alignas(16) char smem[24576];   // 2 bufs x (A 4KB + B 8KB)
  const int tid = threadIdx.x, wave = tid>>6, lane = tid&63;
  const int lr = lane&15, lg = lane>>4;
  const int m0 = blockIdx.x*64, n0 = blockIdx.y*128;
  const int wr = (wave>>1)*32, wc = (wave&1)*64;
  f32x4 acc[2][4] = {};
  const int srowB = wave*32 + (lane>>2);             // B staging row (+i*16)
  const int schk  = (lane&3) ^ ((lane>>3)&3);        // swizzled source granule (B)
  const int rowA  = tid >> 2;                        // A staging row (1 chunk/thread)
  const int schkA = (tid&3) ^ ((tid>>3)&3);          // swizzled source granule (A)
  const int fo    = ((lg ^ ((lr>>1)&3)) << 4);       // swizzled frag byte offset

  auto stage = [&](int kt, int buf){
    char* Ab = smem + buf*12288;
    char* Bb = Ab + 4096;
    async_copy16(A + (size_t)(m0 + rowA)*K + kt + schkA*8, Ab + (wave*16)*64);
    #pragma unroll
    for (int i = 0; i < 2; i++){
      int r = srowB + i*16;
      async_copy16(Bt + (size_t)(n0 + r)*K + kt + schk*8, Bb + (wave*32 + i*16)*64);
    }
  };

  const int NT = K >> 5;
  stage(0, 0);
  for (int t = 0; t < NT; t++){
    const int c = t & 1;
    asm volatile("s_waitcnt vmcnt(0)" ::: "memory");
    __builtin_amdgcn_s_barrier();
    if (t+1 < NT) stage((t+1)<<5, c^1);

    const char* Ac = smem + c*12288;
    const char* Bc = Ac + 4096;
    short8 a[2], b[4];
    #pragma unroll
    for (int mi = 0; mi < 2; mi++)
      a[mi] = *(const short8*)(Ac + (wr + mi*16 + lr)*64 + fo);
    #pragma unroll
    for (int ni = 0; ni < 4; ni++)
      b[ni] = *(const short8*)(Bc + (wc + ni*16 + lr)*64 + fo);
    #pragma unroll
    for (int mi = 0; mi < 2; mi++)
      #pragma unroll
      for (int ni = 0; ni < 4; ni++)
        acc[mi][ni] = __builtin_amdgcn_mfma_f32_16x16x32_bf16(a[mi], b[ni], acc[mi][ni], 0, 0, 0);
  }

  #pragma unroll
  for (int mi = 0; mi < 2; mi++)
  #pragma unroll
  for (int ni = 0; ni < 4; ni++)
  #pragma unroll
  for (int j = 0; j < 4; j++){
    int m = m0 + wr + mi*16 + lg*4 + j;
    int n = n0 + wc + ni*16 + lr;
    outf[(size_t)m*N + n] = acc[mi][ni][j] + bias[n];
  }
}

// ---------------- flash attention: merged causal pair-sweep ----------------
// R15: revert P-pack to software pack_bf2 (v_cvt_pk_bf16_f32 asm corrupted P
// on gfx950 -- m240's warning confirmed). Keep max3 reduce + hoisted offsets.
__launch_bounds__(256, 3)
__global__ void attn_kernel(const u16* __restrict__ q, const u16* __restrict__ k,
                            const u16* __restrict__ vt, u16* __restrict__ aout)
{
  __shared__ alignas(16) char smem[53248];
  const int b1 = blockIdx.x;                 // 0..767
  const int xcd = b1 & 7, grp = b1 >> 3;     // grp 0..95
  const int bh = xcd*6 + (grp >> 4);         // 6 heads per XCD (L2 locality)
  const int p  = grp & 15;                   // lo tile index 0..15
  const int hi = 31 - p;                     // hi tile index 16..31
  const int tid = threadIdx.x, wave = tid>>6, lane = tid&63;
  const int lr = lane&15, lg = lane>>4;
  const int b_ = bh / NH, h_ = bh % NH;
  const u16* qp = q  + (size_t)bh*SEQ*HD;
  const u16* kp = k  + (size_t)bh*SEQ*HD;
  const u16* vp = vt + (size_t)bh*HD*SEQ;
  char* Pw = smem + 32768 + wave*5120;
  const int fswz = (lr&7)<<4;
  const int c8s = (lane&7) ^ (lane>>3);
  const int nkv = hi + 1;

  // hoisted P-LDS write offsets (loop-invariant per ni)
  int po[4];
  #pragma unroll
  for (int ni = 0; ni < 4; ni++){
    int tl = lr + 16*(((ni&1)<<1) | (lg>>1));
    int wb = ((ni>>1)<<2) | ((lg&1)<<1);
    po[ni] = tl*40 + wb*4;
  }

  auto stageKV = [&](int kv0, int buf){
    char* Kb = smem + buf*16384;
    char* Vb = Kb + 8192;
    #pragma unroll
    for (int r = 0; r < 2; r++){
      int row = wave*16 + r*8 + (lane>>3);
      async_copy16(kp + (size_t)(kv0 + row)*HD + c8s*8, Kb + (wave*16 + r*8)*128);
      async_copy16(vp + (size_t)row*SEQ + kv0 + c8s*8,  Vb + (wave*16 + r*8)*128);
    }
  };

  const int qrow[2] = { hi*64 + wave*16 + lr, p*64 + wave*16 + lr };

  short8 bq[2][2];
  #pragma unroll
  for (int h = 0; h < 2; h++)
    #pragma unroll
    for (int ks = 0; ks < 2; ks++)
      bq[h][ks] = *(const short8*)(qp + (size_t)qrow[h]*HD + ks*32 + lg*8);

  float mrow[2] = {-INFINITY, -INFINITY};
  float lsum[2] = {0.f, 0.f};
  f32x4 o[4][2] = {};

  stageKV(0, 0);

  auto softmax_pack = [&](f32x4 (&s)[4][2], int h, bool domask, int kv0, int qr){
    if (domask){
      #pragma unroll
      for (int ni = 0; ni < 4; ni++)
        #pragma unroll
        for (int jj = 0; jj < 4; jj++){
          int col = kv0 + ni*16 + lg*4 + jj;
          if (col > qr) s[ni][h][jj] = -1e30f;
        }
    }
    // max3-shaped 16-value reduce (clang fuses fmaxf(fmaxf(a,b),c) -> v_max3)
    float v0 = fmaxf(fmaxf(s[0][h][0], s[0][h][1]), s[0][h][2]);
    float v1 = fmaxf(fmaxf(s[0][h][3], s[1][h][0]), s[1][h][1]);
    float v2 = fmaxf(fmaxf(s[1][h][2], s[1][h][3]), s[2][h][0]);
    float v3 = fmaxf(fmaxf(s[2][h][1], s[2][h][2]), s[2][h][3]);
    float v4 = fmaxf(fmaxf(s[3][h][0], s[3][h][1]), s[3][h][2]);
    float vloc = fmaxf(fmaxf(fmaxf(v0, v1), fmaxf(v2, v3)), fmaxf(v4, s[3][h][3]));
    if (!__all(vloc - mrow[h] <= 8.0f)){
      float v = fmaxf(vloc, __shfl_xor(vloc, 16));
      v = fmaxf(v, __shfl_xor(v, 32));
      float mn = fmaxf(mrow[h], v);
      float alpha = __builtin_amdgcn_exp2f(mrow[h] - mn);
      mrow[h] = mn;
      lsum[h] *= alpha;
      #pragma unroll
      for (int ni = 0; ni < 4; ni++)
        #pragma unroll
        for (int jj = 0; jj < 4; jj++)
          o[ni][h][jj] *= alpha;
    }
    const float mn = mrow[h];
    char* hb = Pw + h*2560;
    float psum = 0.f;
    #pragma unroll
    for (int ni = 0; ni < 4; ni++){
      float p0 = __builtin_amdgcn_exp2f(s[ni][h][0] - mn);
      float p1 = __builtin_amdgcn_exp2f(s[ni][h][1] - mn);
      float p2 = __builtin_amdgcn_exp2f(s[ni][h][2] - mn);
      float p3 = __builtin_amdgcn_exp2f(s[ni][h][3] - mn);
      psum += (p0+p1) + (p2+p3);
      *(u32*)(hb + po[ni])     = pack_bf2(p0, p1);
      *(u32*)(hb + po[ni] + 4) = pack_bf2(p2, p3);
    }
    lsum[h] += psum;
  };

  auto read_pb = [&](int h, short8& r0, short8& r1){
    const char* hb = Pw + h*2560 + (size_t)lane*40;
    union { u32 w[4]; short8 v; } a, b;
    a.w[0] = *(const u32*)(hb);      a.w[1] = *(const u32*)(hb + 4);
    a.w[2] = *(const u32*)(hb + 8);  a.w[3] = *(const u32*)(hb + 12);
    b.w[0] = *(const u32*)(hb + 16); b.w[1] = *(const u32*)(hb + 20);
    b.w[2] = *(const u32*)(hb + 24); b.w[3] = *(const u32*)(hb + 28);
    r0 = a.v; r1 = b.v;
  };

  int kvb = 0;

  #pragma unroll 1
  for (; kvb <= p; kvb++){
    const int c = kvb & 1;
    const int kv0 = kvb*64;
    asm volatile("s_waitcnt vmcnt(0)" ::: "memory");
    __builtin_amdgcn_s_barrier();
    if (kvb+1 < nkv) stageKV(kv0 + 64, c^1);

    const char* Kb = smem + c*16384;
    const char* Vb = Kb + 8192;

    f32x4 s[4][2] = {};
    __builtin_amdgcn_s_setprio(1);
    #pragma unroll
    for (int ni = 0; ni < 4; ni++){
      short8 k0 = *(const short8*)(Kb + (ni*16+lr)*128 + ((lg*16) ^ fswz));
      short8 k1 = *(const short8*)(Kb + (ni*16+lr)*128 + ((64 + lg*16) ^ fswz));
      #pragma unroll
      for (int h = 0; h < 2; h++){
        s[ni][h] = __builtin_amdgcn_mfma_f32_16x16x32_bf16(k0, bq[h][0], s[ni][h], 0,0,0);
        s[ni][h] = __builtin_amdgcn_mfma_f32_16x16x32_bf16(k1, bq[h][1], s[ni][h], 0,0,0);
      }
    }
    __builtin_amdgcn_s_setprio(0);

    softmax_pack(s, 0, false, kv0, qrow[0]);
    softmax_pack(s, 1, kvb == p, kv0, qrow[1]);

    short8 pb[2][2];
    read_pb(0, pb[0][0], pb[0][1]);
    read_pb(1, pb[1][0], pb[1][1]);

    __builtin_amdgcn_s_setprio(1);
    #pragma unroll
    for (int ni = 0; ni < 4; ni++){
      short8 v0 = *(const short8*)(Vb + (ni*16+lr)*128 + ((lg*16) ^ fswz));
      short8 v1 = *(const short8*)(Vb + (ni*16+lr)*128 + ((64 + lg*16) ^ fswz));
      #pragma unroll
      for (int h = 0; h < 2; h++){
        o[ni][h] = __builtin_amdgcn_mfma_f32_16x16x32_bf16(v0, pb[h][0], o[ni][h], 0,0,0);
        o[ni][h] = __builtin_amdgcn_mfma_f32_16x16x32_bf16(v1, pb[h][1], o[ni][h], 0,0,0);
      }
    }
    __builtin_amdgcn_s_setprio(0);
  }

  #pragma unroll 1
  for (; kvb < nkv; kvb++){
    const int c = kvb & 1;
    const int kv0 = kvb*64;
    asm volatile("s_waitcnt vmcnt(0)" ::: "memory");
    __builtin_amdgcn_s_barrier();
    if (kvb+1 < nkv) stageKV(kv0 + 64, c^1);

    const char* Kb = smem + c*16384;
    const char* Vb = Kb + 8192;

    f32x4 s[4][2];
    #pragma unroll
    for (int ni = 0; ni < 4; ni++) s[ni][0] = (f32x4){0.f,0.f,0.f,0.f};
    __builtin_amdgcn_s_setprio(1);
    #pragma unroll
    for (int ni = 0; ni < 4; ni++){
      short8 k0 = *(const short8*)(Kb + (ni*16+lr)*128 + ((lg*16) ^ fswz));
      short8 k1 = *(const short8*)(Kb + (ni*16+lr)*128 + ((64 + lg*16) ^ fswz));
      s[ni][0] = __builtin_amdgcn_mfma_f32_16x16x32_bf16(k0, bq[0][0], s[ni][0], 0,0,0);
      s[ni][0] = __builtin_amdgcn_mfma_f32_16x16x32_bf16(k1, bq[0][1], s[ni][0], 0,0,0);
    }
    __builtin_amdgcn_s_setprio(0);

    softmax_pack(s, 0, kvb == hi, kv0, qrow[0]);

    short8 pb0, pb1;
    read_pb(0, pb0, pb1);

    __builtin_amdgcn_s_setprio(1);
    #pragma unroll
    for (int ni = 0; ni < 4; ni++){
      short8 v0 = *(const short8*)(Vb + (ni*16+lr)*128 + ((lg*16) ^ fswz));
      short8 v1 = *(const short8*)(Vb + (ni*16+lr)*128 + ((64 + lg*16) ^ fswz));
      o[ni][0] = __builtin_amdgcn_mfma_f32_16x16x32_bf16(v0, pb0, o[ni][0], 0,0,0);
      o[ni][0] = __builtin_amdgcn_mfma_f32_16x16x32_bf16(v1, pb1, o[ni][0], 0,0,0);
    }
    __builtin_amdgcn_s_setprio(0);
  }

  #pragma unroll
  for (int h = 0; h < 2; h++){
    float ls = lsum[h];
    ls += __shfl_xor(ls, 16);
    ls += __shfl_xor(ls, 32);
    float inv = 1.0f / ls;
    u16* orow = aout + ((size_t)b_*SEQ + qrow[h])*D_MODEL + h_*HD;
    #pragma unroll
    for (int ni = 0; ni < 4; ni++){
      ushort4 w;
      w.x = f2bf(o[ni][h][0]*inv);
      w.y = f2bf(o[ni][h][1]*inv);
      w.z = f2bf(o[ni][h][2]*inv);
      w.w = f2bf(o[ni][h][3]*inv);
      *(ushort4*)(orow + ni*16 + lg*4) = w;
    }
  }
}

extern "C" void kernel_launch(void* const* d_in, const int* in_sizes, int n_in,
                              void* d_out, int out_size, void* d_ws, size_t ws_size,
                              hipStream_t stream)
{
  const float* x    = (const float*)d_in[0];
  const float* Wqkv = (const float*)d_in[1];
  const float* bqkv = (const float*)d_in[2];
  const float* Wout = (const float*)d_in[3];
  const float* bout = (const float*)d_in[4];
  float* out = (float*)d_out;
  char* ws = (char*)d_ws;

  // workspace layout (bytes)
  u16* x_bf   = (u16*)(ws + 0);          // 8192x768   bf16 = 12,582,912
  u16* wqkv_t = (u16*)(ws + 12582912);   // 2304x768   bf16 =  3,538,944
  u16* wout_t = (u16*)(ws + 16121856);   //  768x768   bf16 =  1,179,648
  u16* qb     = (u16*)(ws + 17301504);   // [48][2048][64]  = 12,582,912
  u16* kb     = (u16*)(ws + 29884416);   // [48][2048][64]  = 12,582,912
  u16* vtb    = (u16*)(ws + 42467328);   // [48][64][2048]  = 12,582,912
  u16* attnb  = (u16*)(ws + 55050240);   // 8192x768   bf16 = 12,582,912

  prep_kernel<<<6720, 256, 0, stream>>>(x, x_bf, Wqkv, wqkv_t, Wout, wout_t);

  gemm_qkv<<<dim3(64, 12), 256, 0, stream>>>(x_bf, wqkv_t, bqkv,
                                             qb, kb, vtb, MROWS, 3*D_MODEL, D_MODEL);

  attn_kernel<<<768, 256, 0, stream>>>(qb, kb, vtb, attnb);

  gemm_out64<<<dim3(128, 6), 256, 0, stream>>>(attnb, wout_t, bout, out,
                                               MROWS, D_MODEL, D_MODEL);
}